// Round 2
// baseline (281.136 us; speedup 1.0000x reference)
//
#include <hip/hip_runtime.h>
#include <hip/hip_bf16.h>
#include <stdint.h>

// B=4, T=2048, K(=D)=128, H=8, KS=5, DIL=2, PAD=8, M=B*H=32
// scale = 128^0.25 ; inv = 0.29730177875068026

typedef __attribute__((ext_vector_type(8))) short bf16x8;
typedef __attribute__((ext_vector_type(4))) float f32x4;
typedef __attribute__((ext_vector_type(4))) int   i32x4;
typedef unsigned short ushort_t;

__device__ __forceinline__ unsigned short f2bf(float x){
  union{float f; unsigned u;} v; v.f = x;
  unsigned r = v.u + 0x7FFFu + ((v.u >> 16) & 1u);   // RNE
  return (unsigned short)(r >> 16);
}
__device__ __forceinline__ float silu_f(float x){ return x / (1.f + __expf(-x)); }

__device__ __forceinline__ int cvt_pk_bf16(float lo, float hi){
  int r;
  asm("v_cvt_pk_bf16_f32 %0, %1, %2" : "=v"(r) : "v"(lo), "v"(hi));
  return r;
}

__device__ __forceinline__ void async_cp16(void* lds, const void* g){
  __builtin_amdgcn_global_load_lds(
      (const __attribute__((address_space(1))) unsigned int*)g,
      (__attribute__((address_space(3))) unsigned int*)lds, 16, 0, 0);
}

// ---------------------------------------------------------------------------
// prep v2: coalesced + vectorized.  (unchanged)
// ---------------------------------------------------------------------------
__global__ __launch_bounds__(256) void prep(const float* __restrict__ Wq,
                                            const float* __restrict__ Wk,
                                            const float* __restrict__ Wv,
                                            const float* __restrict__ Wu,
                                            const float* __restrict__ x,
                                            ushort_t* __restrict__ W2p,
                                            ushort_t* __restrict__ Wvp,
                                            ushort_t* __restrict__ Wub,
                                            ushort_t* __restrict__ Xpad){
  __shared__ float row[640];
  int n = blockIdx.x;
  int tid = threadIdx.x;
  if (n < 2048){
    int qk = n >> 10, h = (n >> 7) & 7, d = n & 127;
    const float* src = (qk ? Wk : Wq) + (size_t)(d*8 + h)*640;
    if (tid < 160) *(float4*)&row[tid*4] = *(const float4*)&src[tid*4];
    __syncthreads();
    for (int rp = tid; rp < 640; rp += 256){
      int j = rp >> 7, ci = rp & 127;
      W2p[(size_t)n*640 + rp] = f2bf(row[ci*5 + j]);
    }
  } else if (n < 3072){
    int co = n - 2048;
    if (tid < 32){
      float4 v = *(const float4*)&Wv[(size_t)co*128 + tid*4];
      uint2 pv;
      pv.x = (unsigned)cvt_pk_bf16(v.x, v.y);
      pv.y = (unsigned)cvt_pk_bf16(v.z, v.w);
      *(uint2*)&Wvp[(size_t)co*128 + tid*4] = pv;
    }
  } else if (n < 3200){
    int j = n - 3072;
    float4 v = *(const float4*)&Wu[(size_t)j*1024 + tid*4];
    uint2 pv;
    pv.x = (unsigned)cvt_pk_bf16(v.x, v.y);
    pv.y = (unsigned)cvt_pk_bf16(v.z, v.w);
    *(uint2*)&Wub[(size_t)j*1024 + tid*4] = pv;
  } else {
    int idx = n - 3200;              // 0..1027 ; 257 blocks per batch (2056=8*257)
    int b = idx / 257, rblk = idx - b*257;
    int rt = rblk*8 + (tid >> 5);
    int ci4 = (tid & 31) * 4;
    int t = rt - 8;
    uint2 val; val.x = 0u; val.y = 0u;
    if (t >= 0){
      float4 v = *(const float4*)&x[((size_t)(b*2048 + t))*128 + ci4];
      val.x = (unsigned)cvt_pk_bf16(v.x, v.y);
      val.y = (unsigned)cvt_pk_bf16(v.z, v.w);
    }
    *(uint2*)&Xpad[((size_t)(b*2056 + rt))*128 + ci4] = val;
  }
}

// ---------------------------------------------------------------------------
// gemm_qkv (unchanged): qk path dbuf vmcnt(4); v path dbuf vmcnt(4).
// ---------------------------------------------------------------------------
__global__ __launch_bounds__(256) void gemm_qkv(
    const ushort_t* __restrict__ Xpad,  // [4][2056][128]
    const ushort_t* __restrict__ W2p,   // [2048][640]
    const ushort_t* __restrict__ Wvp,   // [1024][128]
    const float* __restrict__ bq, const float* __restrict__ bk,
    ushort_t* __restrict__ Q2, ushort_t* __restrict__ K2,
    ushort_t* __restrict__ V2t)
{
  __shared__ ushort_t As[2][128*32] __attribute__((aligned(16)));
  __shared__ ushort_t Bs[2][128*32] __attribute__((aligned(16)));
  int bt0 = blockIdx.y * 128;
  int tid = threadIdx.x;
  int w = tid >> 6, ln = tid & 63;
  int lc = ln & 15, lg = ln >> 4;
  int mi = (w & 1) * 64, nj = (w >> 1) * 64;
  int srow = ln >> 2;
  int kseg = (ln & 3) * 8;
  int b = bt0 >> 11, tl0 = bt0 & 2047;

  f32x4 acc[4][4];
  #pragma unroll
  for (int si = 0; si < 4; si++)
    #pragma unroll
    for (int sj = 0; sj < 4; sj++) acc[si][sj] = (f32x4){0.f,0.f,0.f,0.f};

  if (blockIdx.x < 16){
    int n0 = blockIdx.x * 128;
    const ushort_t* gA = Xpad + (size_t)(b*2056 + tl0 + w*32 + srow)*128 + kseg;
    const ushort_t* gB = W2p + (size_t)(n0  + w*32 + srow)*640 + kseg;

    auto stageAB = [&](int kk, int bsel){
      int j = kk >> 2, ci0 = (kk & 3) * 32;
      int r0 = kk * 32;
      const ushort_t* a0 = gA + (size_t)(2*j)*128 + ci0;
      async_cp16(&As[bsel][w*1024],       a0);
      async_cp16(&As[bsel][w*1024 + 512], a0 + 16*128);
      async_cp16(&Bs[bsel][w*1024],       gB + r0);
      async_cp16(&Bs[bsel][w*1024 + 512], gB + r0 + 16*640);
    };

    stageAB(0, 0);
    for (int kk = 0; kk < 20; kk++){
      int bsel = kk & 1;
      if (kk + 1 < 20){
        stageAB(kk + 1, bsel ^ 1);
        asm volatile("s_waitcnt vmcnt(4)\n\ts_barrier" ::: "memory");
      } else {
        asm volatile("s_waitcnt vmcnt(0)\n\ts_barrier" ::: "memory");
      }
      bf16x8 af[4], bfr[4];
      #pragma unroll
      for (int si = 0; si < 4; si++)
        af[si] = *(const bf16x8*)&As[bsel][(mi + 16*si + lc)*32 + 8*lg];
      #pragma unroll
      for (int sj = 0; sj < 4; sj++)
        bfr[sj] = *(const bf16x8*)&Bs[bsel][(nj + 16*sj + lc)*32 + 8*lg];
      #pragma unroll
      for (int si = 0; si < 4; si++)
        #pragma unroll
        for (int sj = 0; sj < 4; sj++)
          acc[si][sj] = __builtin_amdgcn_mfma_f32_16x16x32_bf16(af[si], bfr[sj],
                                                                acc[si][sj], 0,0,0);
      asm volatile("s_barrier" ::: "memory");
    }

    const float inv_scale = 0.29730177875068026f;
    int qk = n0 >> 10, h = (n0 >> 7) & 7;
    const float* bias = qk ? bk : bq;
    ushort_t* dst = qk ? K2 : Q2;
    float bv[4];
    #pragma unroll
    for (int sj = 0; sj < 4; sj++) bv[sj] = bias[(nj + 16*sj + lc)*8 + h];

    #pragma unroll
    for (int si = 0; si < 4; si++){
      int btb = bt0 + mi + 16*si + 4*lg;
      #pragma unroll
      for (int r = 0; r < 4; r++){
        int t = btb + r;
        int bb = t >> 11, tl = t & 2047;
        size_t rowoff = ((size_t)(bb*8 + (tl >> 8))*2048 + (tl & 255)*8 + h)*128;
        #pragma unroll
        for (int sj = 0; sj < 4; sj++){
          int d = nj + 16*sj + lc;
          dst[rowoff + d] = f2bf(silu_f(acc[si][sj][r] + bv[sj]) * inv_scale);
        }
      }
    }
  } else {
    int n0 = (blockIdx.x - 16) * 128;
    const ushort_t* gA = Xpad + (size_t)(b*2056 + 8 + tl0 + w*32 + srow)*128 + kseg;
    const ushort_t* gB = Wvp  + (size_t)(n0 + w*32 + srow)*128 + kseg;

    auto stageV = [&](int kk, int bsel){
      int r0 = kk * 32;
      async_cp16(&As[bsel][w*1024],       gA + r0);
      async_cp16(&As[bsel][w*1024 + 512], gA + r0 + 16*128);
      async_cp16(&Bs[bsel][w*1024],       gB + r0);
      async_cp16(&Bs[bsel][w*1024 + 512], gB + r0 + 16*128);
    };

    stageV(0, 0);
    for (int kk = 0; kk < 4; kk++){
      int bsel = kk & 1;
      if (kk + 1 < 4){
        stageV(kk + 1, bsel ^ 1);
        asm volatile("s_waitcnt vmcnt(4)\n\ts_barrier" ::: "memory");
      } else {
        asm volatile("s_waitcnt vmcnt(0)\n\ts_barrier" ::: "memory");
      }
      bf16x8 af[4], bfr[4];
      #pragma unroll
      for (int si = 0; si < 4; si++)
        af[si] = *(const bf16x8*)&As[bsel][(mi + 16*si + lc)*32 + 8*lg];
      #pragma unroll
      for (int sj = 0; sj < 4; sj++)
        bfr[sj] = *(const bf16x8*)&Bs[bsel][(nj + 16*sj + lc)*32 + 8*lg];
      #pragma unroll
      for (int si = 0; si < 4; si++)
        #pragma unroll
        for (int sj = 0; sj < 4; sj++)
          acc[si][sj] = __builtin_amdgcn_mfma_f32_16x16x32_bf16(af[si], bfr[sj],
                                                                acc[si][sj], 0,0,0);
      asm volatile("s_barrier" ::: "memory");
    }

    #pragma unroll
    for (int si = 0; si < 4; si++){
      int btb = bt0 + mi + 16*si + 4*lg;
      #pragma unroll
      for (int r = 0; r < 4; r++){
        int t = btb + r;
        int bb = t >> 11, tl = t & 2047;
        int mm = bb*8 + (tl >> 8);
        int tpb = (tl & 255)*8;
        #pragma unroll
        for (int sj = 0; sj < 4; sj++){
          int co = n0 + nj + 16*sj + lc;
          int d = co >> 3, hh = co & 7;
          V2t[((size_t)mm*128 + d)*2048 + tpb + hh] = f2bf(silu_f(acc[si][sj][r]));
        }
      }
    }
  }
}

// ---------------------------------------------------------------------------
// Flash attention — frozen round-8/10/13/14 structure, with ONE change:
// V is no longer staged in LDS. vf fragments are read directly from global
// (V2t is L2-resident per-XCD: 4 heads x 1MB K+V = 4MB; the 16KB V tile is
// re-read by 4 waves -> L1-served). This removes 8 of 12 staging ops/step,
// halves the vmcnt drain (8->4), removes 16 ds_read_b128/step, and the vf
// global loads have no LDS/barrier dependency so they hoist under QK/softmax.
// LDS 64KB -> 32KB. Register pressure kept at frozen level (in-place loads).
// ---------------------------------------------------------------------------
__global__ __launch_bounds__(256) void attn(
    const ushort_t* __restrict__ Q2,   // [32][2048][128]
    const ushort_t* __restrict__ K2,   // [32][2048][128]
    const ushort_t* __restrict__ V2t,  // [32][128][2048]
    ushort_t* __restrict__ O2)         // [8192][1024] bf16
{
  __shared__ i32x4 kbuf[2][1024];      // [buf][(st*4+c)*64 + lane]  16KB each

  int bid = blockIdx.x;                      // 512 blocks
  int m   = ((bid & 7) << 2) | ((bid >> 3) & 3);  // XCD-L2 locality swizzle
  int ip  = bid >> 5;                        // pair index 0..15
  int tid = threadIdx.x;
  int w = tid >> 6, l = tid & 63;
  int lc = l & 15, lg = l >> 4;

  int iA = 31 - ip, iB = ip;
  int ntA = iA + 1;
  const int nt = 33;

  const size_t mQ = (size_t)m * 2048;
  const ushort_t* Kbase = K2  + mQ * 128;
  const ushort_t* Vbase = V2t + (size_t)m * 128 * 2048;
  int hb = m & 7, bI = m >> 3;

  int psel[4];
  #pragma unroll
  for (int w2 = 0; w2 < 4; w2++)
    psel[w2] = ((((2*(lg & 1) + (w2 >> 1)) << 4) | lc) << 2);

  auto stage = [&](int s0, int bsel){
    const ushort_t* krow = Kbase + (size_t)(s0 + w*16 + lc)*128 + 8*lg;
    #pragma unroll
    for (int c = 0; c < 4; c++)
      async_cp16(&kbuf[bsel][(w*4 + c)*64], krow + 32*c);
  };

  int qb = iA*64 + w*16;
  bf16x8 qfrag[4];
  {
    const ushort_t* qp = Q2 + (mQ + qb + lc)*128 + 8*lg;
    #pragma unroll
    for (int c = 0; c < 4; c++) qfrag[c] = *(const bf16x8*)(qp + 32*c);
  }
  f32x4 oacc[8];
  #pragma unroll
  for (int dt = 0; dt < 8; dt++) oacc[dt] = (f32x4){0.f,0.f,0.f,0.f};
  float lrow = 0.f;

  const float LOG2E = 1.4426950408889634f;
  const float EOFF  = -11.541560327111707f;   // -8 * log2(e)

  stage(0, 0);

  for (int step = 0; step < nt; step++){
    if (step == ntA){
      float lt = lrow;
      lt += __shfl_xor(lt, 16);
      lt += __shfl_xor(lt, 32);
      float invl = 1.f / lt;
      size_t obase = ((size_t)(bI*2048 + qb + lc))*1024 + hb*128 + 4*lg;
      #pragma unroll
      for (int dt = 0; dt < 8; dt++){
        uint2 val;
        val.x = (unsigned)cvt_pk_bf16(oacc[dt][0]*invl, oacc[dt][1]*invl);
        val.y = (unsigned)cvt_pk_bf16(oacc[dt][2]*invl, oacc[dt][3]*invl);
        *(uint2*)&O2[obase + 16*dt] = val;
      }
      qb = iB*64 + w*16;
      const ushort_t* qp = Q2 + (mQ + qb + lc)*128 + 8*lg;
      #pragma unroll
      for (int c = 0; c < 4; c++) qfrag[c] = *(const bf16x8*)(qp + 32*c);
      #pragma unroll
      for (int dt = 0; dt < 8; dt++) oacc[dt] = (f32x4){0.f,0.f,0.f,0.f};
      lrow = 0.f;
    }
    int local = (step < ntA) ? step : step - ntA;
    bool isLast = (step == ntA - 1) || (step == nt - 1);
    int s0 = local * 64;
    int bsel = step & 1;

    if (step + 1 < nt){
      int nl = (step + 1 < ntA) ? step + 1 : step + 1 - ntA;
      stage(nl*64, bsel ^ 1);
      asm volatile("s_waitcnt vmcnt(4)\n\ts_barrier" ::: "memory");
    } else {
      asm volatile("s_waitcnt vmcnt(0)\n\ts_barrier" ::: "memory");
    }

    f32x4 sacc[4];
    #pragma unroll
    for (int st = 0; st < 4; st++){
      f32x4 a2 = (f32x4){0.f,0.f,0.f,0.f};
      #pragma unroll
      for (int c = 0; c < 4; c++){
        bf16x8 kf = *(bf16x8*)&kbuf[bsel][(st*4 + c)*64 + l];
        a2 = __builtin_amdgcn_mfma_f32_16x16x32_bf16(kf, qfrag[c], a2, 0, 0, 0);
      }
      sacc[st] = a2;
    }
    if (isLast){
      int qg = qb + lc;
      #pragma unroll
      for (int st = 0; st < 4; st++)
        #pragma unroll
        for (int r = 0; r < 4; r++){
          int sg = s0 + st*16 + 4*lg + r;
          if (sg > qg) sacc[st][r] = -1e30f;
        }
    }

    float p_[4][4];
    #pragma unroll
    for (int st = 0; st < 4; st++)
      #pragma unroll
      for (int r = 0; r < 4; r++){
        float sv = fminf(fmaf(sacc[st][r], LOG2E, EOFF), 108.f);
        float pv = __builtin_amdgcn_exp2f(sv);
        p_[st][r] = pv;
        lrow += pv;
      }

    // V fragments direct from global (L1/L2-resident); same element mapping
    // as the old vbuf staging: V2t[m][(dt*16+lc)*2048 + s0 + ks*32 + 8*lg]
    const ushort_t* vstep = Vbase + s0 + 8*lg;
    #pragma unroll
    for (int ks = 0; ks < 2; ks++){
      int pk0[2], pk1[2];
      #pragma unroll
      for (int pa = 0; pa < 2; pa++){
        pk0[pa] = cvt_pk_bf16(p_[2*ks][2*pa],   p_[2*ks][2*pa+1]);
        pk1[pa] = cvt_pk_bf16(p_[2*ks+1][2*pa], p_[2*ks+1][2*pa+1]);
      }
      union { int i[4]; bf16x8 v; } bfr;
      #pragma unroll
      for (int w2 = 0; w2 < 4; w2++){
        int v0 = __builtin_amdgcn_ds_bpermute(psel[w2], pk0[w2 & 1]);
        int v1 = __builtin_amdgcn_ds_bpermute(psel[w2], pk1[w2 & 1]);
        bfr.i[w2] = (lg >> 1) ? v1 : v0;
      }
      #pragma unroll
      for (int dt = 0; dt < 8; dt++){
        bf16x8 vf = *(const bf16x8*)(vstep + (size_t)(dt*16 + lc)*2048 + ks*32);
        oacc[dt] = __builtin_amdgcn_mfma_f32_16x16x32_bf16(vf, bfr.v, oacc[dt], 0, 0, 0);
      }
    }
    asm volatile("s_barrier" ::: "memory");
  }

  float lt = lrow;
  lt += __shfl_xor(lt, 16);
  lt += __shfl_xor(lt, 32);
  float invl = 1.f / lt;
  size_t obase = ((size_t)(bI*2048 + qb + lc))*1024 + hb*128 + 4*lg;
  #pragma unroll
  for (int dt = 0; dt < 8; dt++){
    uint2 val;
    val.x = (unsigned)cvt_pk_bf16(oacc[dt][0]*invl, oacc[dt][1]*invl);
    val.y = (unsigned)cvt_pk_bf16(oacc[dt][2]*invl, oacc[dt][3]*invl);
    *(uint2*)&O2[obase + 16*dt] = val;
  }
}

// ---------------------------------------------------------------------------
// finalmm (unchanged): dbuf, vmcnt(2).
// ---------------------------------------------------------------------------
__global__ __launch_bounds__(256) void finalmm(
    const ushort_t* __restrict__ O2,    // [8192][1024] bf16
    const ushort_t* __restrict__ Wub,   // [128][1024] bf16
    const float* __restrict__ bu,
    float* __restrict__ out)            // [8192][128]
{
  __shared__ ushort_t As[2][32*32]  __attribute__((aligned(16)));   // 2x2 KB
  __shared__ ushort_t Bs[2][128*32] __attribute__((aligned(16)));   // 2x8 KB
  int bt0 = blockIdx.x * 32;
  int tid = threadIdx.x;
  int w = tid >> 6, ln = tid & 63;
  int lc = ln & 15, lg = ln >> 4;
  int nj = w * 32;
  int srow = ln >> 2;
  int kseg = (ln & 3) * 8;

  f32x4 acc[2][2];
  #pragma unroll
  for (int si = 0; si < 2; si++)
    #pragma unroll
    for (int sj = 0; sj < 2; sj++) acc[si][sj] = (f32x4){0.f,0.f,0.f,0.f};

  const ushort_t* gA = O2  + (size_t)(bt0 + (w & 1)*16 + srow)*1024 + kseg;
  const ushort_t* gB = Wub + (size_t)(w*32 + srow)*1024 + kseg;

  auto stageF = [&](int kk, int bsel){
    int r0 = kk * 32;
    if (w < 2) async_cp16(&As[bsel][w*512], gA + r0);
    async_cp16(&Bs[bsel][w*1024],       gB + r0);
    async_cp16(&Bs[bsel][w*1024 + 512], gB + r0 + 16*1024);
  };

  stageF(0, 0);
  for (int kk = 0; kk < 32; kk++){
    int bsel = kk & 1;
    if (kk + 1 < 32){
      stageF(kk + 1, bsel ^ 1);
      asm volatile("s_waitcnt vmcnt(2)\n\ts_barrier" ::: "memory");
    } else {
      asm volatile("s_waitcnt vmcnt(0)\n\ts_barrier" ::: "memory");
    }
    bf16x8 af[2], bfr[2];
    #pragma unroll
    for (int si = 0; si < 2; si++)
      af[si] = *(const bf16x8*)&As[bsel][(16*si + lc)*32 + 8*lg];
    #pragma unroll
    for (int sj = 0; sj < 2; sj++)
      bfr[sj] = *(const bf16x8*)&Bs[bsel][(nj + 16*sj + lc)*32 + 8*lg];
    #pragma unroll
    for (int si = 0; si < 2; si++)
      #pragma unroll
      for (int sj = 0; sj < 2; sj++)
        acc[si][sj] = __builtin_amdgcn_mfma_f32_16x16x32_bf16(af[si], bfr[sj],
                                                              acc[si][sj], 0,0,0);
    asm volatile("s_barrier" ::: "memory");
  }

  float bv[2];
  #pragma unroll
  for (int sj = 0; sj < 2; sj++) bv[sj] = bu[nj + 16*sj + lc];
  #pragma unroll
  for (int si = 0; si < 2; si++)
    #pragma unroll
    for (int r = 0; r < 4; r++){
      int t = bt0 + 16*si + 4*lg + r;
      #pragma unroll
      for (int sj = 0; sj < 2; sj++)
        out[(size_t)t*128 + nj + 16*sj + lc] = silu_f(acc[si][sj][r] + bv[sj]);
    }
}

// ---------------------------------------------------------------------------
extern "C" void kernel_launch(void* const* d_in, const int* in_sizes, int n_in,
                              void* d_out, int out_size, void* d_ws, size_t ws_size,
                              hipStream_t stream) {
  const float* x  = (const float*)d_in[0];
  const float* Wq = (const float*)d_in[1];
  const float* bq = (const float*)d_in[2];
  const float* Wk = (const float*)d_in[3];
  const float* bk = (const float*)d_in[4];
  const float* Wv = (const float*)d_in[5];
  const float* Wu = (const float*)d_in[6];
  const float* bu = (const float*)d_in[7];
  float* out = (float*)d_out;

  // Workspace layout (generous slack; Xpad is 2,105,344 B)
  char* ws = (char*)d_ws;
  ushort_t* Q2   = (ushort_t*)(ws + 0);            // 16 MB
  ushort_t* K2   = (ushort_t*)(ws + 16777216);     // 16 MB
  ushort_t* V2t  = (ushort_t*)(ws + 33554432);     // 16 MB
  ushort_t* O2   = (ushort_t*)(ws + 50331648);     // 16 MB (bf16 [8192][1024])
  ushort_t* Xpad = (ushort_t*)(ws + 67108864);     // 2.008 MB
  ushort_t* W2p  = (ushort_t*)(ws + 70254592);     // 2.5 MB
  ushort_t* Wvp  = (ushort_t*)(ws + 73400320);     // 0.25 MB
  ushort_t* Wub  = (ushort_t*)(ws + 74448896);     // 0.25 MB

  prep<<<dim3(4228, 1, 1), 256, 0, stream>>>(Wq, Wk, Wv, Wu, x,
                                             W2p, Wvp, Wub, Xpad);

  gemm_qkv<<<dim3(24, 64, 1), 256, 0, stream>>>(Xpad, W2p, Wvp, bq, bk,
                                                Q2, K2, V2t);

  attn<<<dim3(512, 1, 1), 256, 0, stream>>>(Q2, K2, V2t, O2);
  finalmm<<<dim3(256, 1, 1), 256, 0, stream>>>(O2, Wub, bu, out);
}

// Round 3
// 207.705 us; speedup vs baseline: 1.3535x; 1.3535x over previous
//
#include <hip/hip_runtime.h>
#include <hip/hip_bf16.h>
#include <stdint.h>

// B=4, T=2048, K(=D)=128, H=8, KS=5, DIL=2, PAD=8, M=B*H=32
// scale = 128^0.25 ; inv = 0.29730177875068026

typedef __attribute__((ext_vector_type(8))) short bf16x8;
typedef __attribute__((ext_vector_type(4))) float f32x4;
typedef __attribute__((ext_vector_type(4))) int   i32x4;
typedef unsigned short ushort_t;

__device__ __forceinline__ unsigned short f2bf(float x){
  union{float f; unsigned u;} v; v.f = x;
  unsigned r = v.u + 0x7FFFu + ((v.u >> 16) & 1u);   // RNE
  return (unsigned short)(r >> 16);
}
__device__ __forceinline__ float silu_f(float x){ return x / (1.f + __expf(-x)); }

__device__ __forceinline__ int cvt_pk_bf16(float lo, float hi){
  int r;
  asm("v_cvt_pk_bf16_f32 %0, %1, %2" : "=v"(r) : "v"(lo), "v"(hi));
  return r;
}

__device__ __forceinline__ void async_cp16(void* lds, const void* g){
  __builtin_amdgcn_global_load_lds(
      (const __attribute__((address_space(1))) unsigned int*)g,
      (__attribute__((address_space(3))) unsigned int*)lds, 16, 0, 0);
}

// ---------------------------------------------------------------------------
// prep v2: coalesced + vectorized.  (unchanged)
// ---------------------------------------------------------------------------
__global__ __launch_bounds__(256) void prep(const float* __restrict__ Wq,
                                            const float* __restrict__ Wk,
                                            const float* __restrict__ Wv,
                                            const float* __restrict__ Wu,
                                            const float* __restrict__ x,
                                            ushort_t* __restrict__ W2p,
                                            ushort_t* __restrict__ Wvp,
                                            ushort_t* __restrict__ Wub,
                                            ushort_t* __restrict__ Xpad){
  __shared__ float row[640];
  int n = blockIdx.x;
  int tid = threadIdx.x;
  if (n < 2048){
    int qk = n >> 10, h = (n >> 7) & 7, d = n & 127;
    const float* src = (qk ? Wk : Wq) + (size_t)(d*8 + h)*640;
    if (tid < 160) *(float4*)&row[tid*4] = *(const float4*)&src[tid*4];
    __syncthreads();
    for (int rp = tid; rp < 640; rp += 256){
      int j = rp >> 7, ci = rp & 127;
      W2p[(size_t)n*640 + rp] = f2bf(row[ci*5 + j]);
    }
  } else if (n < 3072){
    int co = n - 2048;
    if (tid < 32){
      float4 v = *(const float4*)&Wv[(size_t)co*128 + tid*4];
      uint2 pv;
      pv.x = (unsigned)cvt_pk_bf16(v.x, v.y);
      pv.y = (unsigned)cvt_pk_bf16(v.z, v.w);
      *(uint2*)&Wvp[(size_t)co*128 + tid*4] = pv;
    }
  } else if (n < 3200){
    int j = n - 3072;
    float4 v = *(const float4*)&Wu[(size_t)j*1024 + tid*4];
    uint2 pv;
    pv.x = (unsigned)cvt_pk_bf16(v.x, v.y);
    pv.y = (unsigned)cvt_pk_bf16(v.z, v.w);
    *(uint2*)&Wub[(size_t)j*1024 + tid*4] = pv;
  } else {
    int idx = n - 3200;              // 0..1027 ; 257 blocks per batch (2056=8*257)
    int b = idx / 257, rblk = idx - b*257;
    int rt = rblk*8 + (tid >> 5);
    int ci4 = (tid & 31) * 4;
    int t = rt - 8;
    uint2 val; val.x = 0u; val.y = 0u;
    if (t >= 0){
      float4 v = *(const float4*)&x[((size_t)(b*2048 + t))*128 + ci4];
      val.x = (unsigned)cvt_pk_bf16(v.x, v.y);
      val.y = (unsigned)cvt_pk_bf16(v.z, v.w);
    }
    *(uint2*)&Xpad[((size_t)(b*2056 + rt))*128 + ci4] = val;
  }
}

// ---------------------------------------------------------------------------
// gemm_qkv (unchanged): qk path dbuf vmcnt(4); v path dbuf vmcnt(4).
// ---------------------------------------------------------------------------
__global__ __launch_bounds__(256) void gemm_qkv(
    const ushort_t* __restrict__ Xpad,  // [4][2056][128]
    const ushort_t* __restrict__ W2p,   // [2048][640]
    const ushort_t* __restrict__ Wvp,   // [1024][128]
    const float* __restrict__ bq, const float* __restrict__ bk,
    ushort_t* __restrict__ Q2, ushort_t* __restrict__ K2,
    ushort_t* __restrict__ V2t)
{
  __shared__ ushort_t As[2][128*32] __attribute__((aligned(16)));
  __shared__ ushort_t Bs[2][128*32] __attribute__((aligned(16)));
  int bt0 = blockIdx.y * 128;
  int tid = threadIdx.x;
  int w = tid >> 6, ln = tid & 63;
  int lc = ln & 15, lg = ln >> 4;
  int mi = (w & 1) * 64, nj = (w >> 1) * 64;
  int srow = ln >> 2;
  int kseg = (ln & 3) * 8;
  int b = bt0 >> 11, tl0 = bt0 & 2047;

  f32x4 acc[4][4];
  #pragma unroll
  for (int si = 0; si < 4; si++)
    #pragma unroll
    for (int sj = 0; sj < 4; sj++) acc[si][sj] = (f32x4){0.f,0.f,0.f,0.f};

  if (blockIdx.x < 16){
    int n0 = blockIdx.x * 128;
    const ushort_t* gA = Xpad + (size_t)(b*2056 + tl0 + w*32 + srow)*128 + kseg;
    const ushort_t* gB = W2p + (size_t)(n0  + w*32 + srow)*640 + kseg;

    auto stageAB = [&](int kk, int bsel){
      int j = kk >> 2, ci0 = (kk & 3) * 32;
      int r0 = kk * 32;
      const ushort_t* a0 = gA + (size_t)(2*j)*128 + ci0;
      async_cp16(&As[bsel][w*1024],       a0);
      async_cp16(&As[bsel][w*1024 + 512], a0 + 16*128);
      async_cp16(&Bs[bsel][w*1024],       gB + r0);
      async_cp16(&Bs[bsel][w*1024 + 512], gB + r0 + 16*640);
    };

    stageAB(0, 0);
    for (int kk = 0; kk < 20; kk++){
      int bsel = kk & 1;
      if (kk + 1 < 20){
        stageAB(kk + 1, bsel ^ 1);
        asm volatile("s_waitcnt vmcnt(4)\n\ts_barrier" ::: "memory");
      } else {
        asm volatile("s_waitcnt vmcnt(0)\n\ts_barrier" ::: "memory");
      }
      bf16x8 af[4], bfr[4];
      #pragma unroll
      for (int si = 0; si < 4; si++)
        af[si] = *(const bf16x8*)&As[bsel][(mi + 16*si + lc)*32 + 8*lg];
      #pragma unroll
      for (int sj = 0; sj < 4; sj++)
        bfr[sj] = *(const bf16x8*)&Bs[bsel][(nj + 16*sj + lc)*32 + 8*lg];
      #pragma unroll
      for (int si = 0; si < 4; si++)
        #pragma unroll
        for (int sj = 0; sj < 4; sj++)
          acc[si][sj] = __builtin_amdgcn_mfma_f32_16x16x32_bf16(af[si], bfr[sj],
                                                                acc[si][sj], 0,0,0);
      asm volatile("s_barrier" ::: "memory");
    }

    const float inv_scale = 0.29730177875068026f;
    int qk = n0 >> 10, h = (n0 >> 7) & 7;
    const float* bias = qk ? bk : bq;
    ushort_t* dst = qk ? K2 : Q2;
    float bv[4];
    #pragma unroll
    for (int sj = 0; sj < 4; sj++) bv[sj] = bias[(nj + 16*sj + lc)*8 + h];

    #pragma unroll
    for (int si = 0; si < 4; si++){
      int btb = bt0 + mi + 16*si + 4*lg;
      #pragma unroll
      for (int r = 0; r < 4; r++){
        int t = btb + r;
        int bb = t >> 11, tl = t & 2047;
        size_t rowoff = ((size_t)(bb*8 + (tl >> 8))*2048 + (tl & 255)*8 + h)*128;
        #pragma unroll
        for (int sj = 0; sj < 4; sj++){
          int d = nj + 16*sj + lc;
          dst[rowoff + d] = f2bf(silu_f(acc[si][sj][r] + bv[sj]) * inv_scale);
        }
      }
    }
  } else {
    int n0 = (blockIdx.x - 16) * 128;
    const ushort_t* gA = Xpad + (size_t)(b*2056 + 8 + tl0 + w*32 + srow)*128 + kseg;
    const ushort_t* gB = Wvp  + (size_t)(n0 + w*32 + srow)*128 + kseg;

    auto stageV = [&](int kk, int bsel){
      int r0 = kk * 32;
      async_cp16(&As[bsel][w*1024],       gA + r0);
      async_cp16(&As[bsel][w*1024 + 512], gA + r0 + 16*128);
      async_cp16(&Bs[bsel][w*1024],       gB + r0);
      async_cp16(&Bs[bsel][w*1024 + 512], gB + r0 + 16*128);
    };

    stageV(0, 0);
    for (int kk = 0; kk < 4; kk++){
      int bsel = kk & 1;
      if (kk + 1 < 4){
        stageV(kk + 1, bsel ^ 1);
        asm volatile("s_waitcnt vmcnt(4)\n\ts_barrier" ::: "memory");
      } else {
        asm volatile("s_waitcnt vmcnt(0)\n\ts_barrier" ::: "memory");
      }
      bf16x8 af[4], bfr[4];
      #pragma unroll
      for (int si = 0; si < 4; si++)
        af[si] = *(const bf16x8*)&As[bsel][(mi + 16*si + lc)*32 + 8*lg];
      #pragma unroll
      for (int sj = 0; sj < 4; sj++)
        bfr[sj] = *(const bf16x8*)&Bs[bsel][(nj + 16*sj + lc)*32 + 8*lg];
      #pragma unroll
      for (int si = 0; si < 4; si++)
        #pragma unroll
        for (int sj = 0; sj < 4; sj++)
          acc[si][sj] = __builtin_amdgcn_mfma_f32_16x16x32_bf16(af[si], bfr[sj],
                                                                acc[si][sj], 0,0,0);
      asm volatile("s_barrier" ::: "memory");
    }

    #pragma unroll
    for (int si = 0; si < 4; si++){
      int btb = bt0 + mi + 16*si + 4*lg;
      #pragma unroll
      for (int r = 0; r < 4; r++){
        int t = btb + r;
        int bb = t >> 11, tl = t & 2047;
        int mm = bb*8 + (tl >> 8);
        int tpb = (tl & 255)*8;
        #pragma unroll
        for (int sj = 0; sj < 4; sj++){
          int co = n0 + nj + 16*sj + lc;
          int d = co >> 3, hh = co & 7;
          V2t[((size_t)mm*128 + d)*2048 + tpb + hh] = f2bf(silu_f(acc[si][sj][r]));
        }
      }
    }
  }
}

// ---------------------------------------------------------------------------
// Flash attention — frozen round-8/10/13/14 structure (84 us verified),
// restored EXACTLY, plus ONE register-neutral change: s_setprio(1) around
// the QK and PV MFMA clusters (T5; measured +4-7% on attn, learn_hip m191).
// Mechanism: 2 independent blocks/CU at different phases; prioritize the
// MFMA-issuing waves over the other block's staging/softmax waves.
// ---------------------------------------------------------------------------
__global__ __launch_bounds__(256) void attn(
    const ushort_t* __restrict__ Q2,   // [32][2048][128]
    const ushort_t* __restrict__ K2,   // [32][2048][128]
    const ushort_t* __restrict__ V2t,  // [32][128][2048]
    ushort_t* __restrict__ O2)         // [8192][1024] bf16
{
  __shared__ i32x4 kbuf[2][1024];      // [buf][(st*4+c)*64 + lane]  16KB each
  __shared__ i32x4 vbuf[2][1024];      // [buf][(dt*2+ks)*64 + lane] 16KB each

  int bid = blockIdx.x;                      // 512 blocks
  int m   = ((bid & 7) << 2) | ((bid >> 3) & 3);  // XCD-L2 locality swizzle
  int ip  = bid >> 5;                        // pair index 0..15
  int tid = threadIdx.x;
  int w = tid >> 6, l = tid & 63;
  int lc = l & 15, lg = l >> 4;

  int iA = 31 - ip, iB = ip;
  int ntA = iA + 1;
  const int nt = 33;

  const size_t mQ = (size_t)m * 2048;
  const ushort_t* Kbase = K2  + mQ * 128;
  const ushort_t* Vbase = V2t + (size_t)m * 128 * 2048;
  int hb = m & 7, bI = m >> 3;

  int psel[4];
  #pragma unroll
  for (int w2 = 0; w2 < 4; w2++)
    psel[w2] = ((((2*(lg & 1) + (w2 >> 1)) << 4) | lc) << 2);

  auto stage = [&](int s0, int bsel){
    const ushort_t* krow = Kbase + (size_t)(s0 + w*16 + lc)*128 + 8*lg;
    #pragma unroll
    for (int c = 0; c < 4; c++)
      async_cp16(&kbuf[bsel][(w*4 + c)*64], krow + 32*c);
    #pragma unroll
    for (int j = 0; j < 4; j++){
      int dt = w*2 + (j >> 1);
      const ushort_t* vrow = Vbase + (size_t)(dt*16 + lc)*2048
                             + s0 + (j & 1)*32 + 8*lg;
      async_cp16(&vbuf[bsel][(w*4 + j)*64], vrow);
    }
  };

  int qb = iA*64 + w*16;
  bf16x8 qfrag[4];
  {
    const ushort_t* qp = Q2 + (mQ + qb + lc)*128 + 8*lg;
    #pragma unroll
    for (int c = 0; c < 4; c++) qfrag[c] = *(const bf16x8*)(qp + 32*c);
  }
  f32x4 oacc[8];
  #pragma unroll
  for (int dt = 0; dt < 8; dt++) oacc[dt] = (f32x4){0.f,0.f,0.f,0.f};
  float lrow = 0.f;

  const float LOG2E = 1.4426950408889634f;
  const float EOFF  = -11.541560327111707f;   // -8 * log2(e)

  stage(0, 0);

  for (int step = 0; step < nt; step++){
    if (step == ntA){
      float lt = lrow;
      lt += __shfl_xor(lt, 16);
      lt += __shfl_xor(lt, 32);
      float invl = 1.f / lt;
      size_t obase = ((size_t)(bI*2048 + qb + lc))*1024 + hb*128 + 4*lg;
      #pragma unroll
      for (int dt = 0; dt < 8; dt++){
        uint2 val;
        val.x = (unsigned)cvt_pk_bf16(oacc[dt][0]*invl, oacc[dt][1]*invl);
        val.y = (unsigned)cvt_pk_bf16(oacc[dt][2]*invl, oacc[dt][3]*invl);
        *(uint2*)&O2[obase + 16*dt] = val;
      }
      qb = iB*64 + w*16;
      const ushort_t* qp = Q2 + (mQ + qb + lc)*128 + 8*lg;
      #pragma unroll
      for (int c = 0; c < 4; c++) qfrag[c] = *(const bf16x8*)(qp + 32*c);
      #pragma unroll
      for (int dt = 0; dt < 8; dt++) oacc[dt] = (f32x4){0.f,0.f,0.f,0.f};
      lrow = 0.f;
    }
    int local = (step < ntA) ? step : step - ntA;
    bool isLast = (step == ntA - 1) || (step == nt - 1);
    int s0 = local * 64;
    int bsel = step & 1;

    if (step + 1 < nt){
      int nl = (step + 1 < ntA) ? step + 1 : step + 1 - ntA;
      stage(nl*64, bsel ^ 1);
      asm volatile("s_waitcnt vmcnt(8)\n\ts_barrier" ::: "memory");
    } else {
      asm volatile("s_waitcnt vmcnt(0)\n\ts_barrier" ::: "memory");
    }

    f32x4 sacc[4];
    __builtin_amdgcn_s_setprio(1);
    #pragma unroll
    for (int st = 0; st < 4; st++){
      f32x4 a2 = (f32x4){0.f,0.f,0.f,0.f};
      #pragma unroll
      for (int c = 0; c < 4; c++){
        bf16x8 kf = *(bf16x8*)&kbuf[bsel][(st*4 + c)*64 + l];
        a2 = __builtin_amdgcn_mfma_f32_16x16x32_bf16(kf, qfrag[c], a2, 0, 0, 0);
      }
      sacc[st] = a2;
    }
    __builtin_amdgcn_s_setprio(0);
    if (isLast){
      int qg = qb + lc;
      #pragma unroll
      for (int st = 0; st < 4; st++)
        #pragma unroll
        for (int r = 0; r < 4; r++){
          int sg = s0 + st*16 + 4*lg + r;
          if (sg > qg) sacc[st][r] = -1e30f;
        }
    }

    float p_[4][4];
    #pragma unroll
    for (int st = 0; st < 4; st++)
      #pragma unroll
      for (int r = 0; r < 4; r++){
        float sv = fminf(fmaf(sacc[st][r], LOG2E, EOFF), 108.f);
        float pv = __builtin_amdgcn_exp2f(sv);
        p_[st][r] = pv;
        lrow += pv;
      }

    #pragma unroll
    for (int ks = 0; ks < 2; ks++){
      int pk0[2], pk1[2];
      #pragma unroll
      for (int pa = 0; pa < 2; pa++){
        pk0[pa] = cvt_pk_bf16(p_[2*ks][2*pa],   p_[2*ks][2*pa+1]);
        pk1[pa] = cvt_pk_bf16(p_[2*ks+1][2*pa], p_[2*ks+1][2*pa+1]);
      }
      union { int i[4]; bf16x8 v; } bfr;
      #pragma unroll
      for (int w2 = 0; w2 < 4; w2++){
        int v0 = __builtin_amdgcn_ds_bpermute(psel[w2], pk0[w2 & 1]);
        int v1 = __builtin_amdgcn_ds_bpermute(psel[w2], pk1[w2 & 1]);
        bfr.i[w2] = (lg >> 1) ? v1 : v0;
      }
      __builtin_amdgcn_s_setprio(1);
      #pragma unroll
      for (int dt = 0; dt < 8; dt++){
        bf16x8 vf = *(bf16x8*)&vbuf[bsel][(dt*2 + ks)*64 + l];
        oacc[dt] = __builtin_amdgcn_mfma_f32_16x16x32_bf16(vf, bfr.v, oacc[dt], 0, 0, 0);
      }
      __builtin_amdgcn_s_setprio(0);
    }
    asm volatile("s_barrier" ::: "memory");
  }

  float lt = lrow;
  lt += __shfl_xor(lt, 16);
  lt += __shfl_xor(lt, 32);
  float invl = 1.f / lt;
  size_t obase = ((size_t)(bI*2048 + qb + lc))*1024 + hb*128 + 4*lg;
  #pragma unroll
  for (int dt = 0; dt < 8; dt++){
    uint2 val;
    val.x = (unsigned)cvt_pk_bf16(oacc[dt][0]*invl, oacc[dt][1]*invl);
    val.y = (unsigned)cvt_pk_bf16(oacc[dt][2]*invl, oacc[dt][3]*invl);
    *(uint2*)&O2[obase + 16*dt] = val;
  }
}

// ---------------------------------------------------------------------------
// finalmm (unchanged): dbuf, vmcnt(2).
// ---------------------------------------------------------------------------
__global__ __launch_bounds__(256) void finalmm(
    const ushort_t* __restrict__ O2,    // [8192][1024] bf16
    const ushort_t* __restrict__ Wub,   // [128][1024] bf16
    const float* __restrict__ bu,
    float* __restrict__ out)            // [8192][128]
{
  __shared__ ushort_t As[2][32*32]  __attribute__((aligned(16)));   // 2x2 KB
  __shared__ ushort_t Bs[2][128*32] __attribute__((aligned(16)));   // 2x8 KB
  int bt0 = blockIdx.x * 32;
  int tid = threadIdx.x;
  int w = tid >> 6, ln = tid & 63;
  int lc = ln & 15, lg = ln >> 4;
  int nj = w * 32;
  int srow = ln >> 2;
  int kseg = (ln & 3) * 8;

  f32x4 acc[2][2];
  #pragma unroll
  for (int si = 0; si < 2; si++)
    #pragma unroll
    for (int sj = 0; sj < 2; sj++) acc[si][sj] = (f32x4){0.f,0.f,0.f,0.f};

  const ushort_t* gA = O2  + (size_t)(bt0 + (w & 1)*16 + srow)*1024 + kseg;
  const ushort_t* gB = Wub + (size_t)(w*32 + srow)*1024 + kseg;

  auto stageF = [&](int kk, int bsel){
    int r0 = kk * 32;
    if (w < 2) async_cp16(&As[bsel][w*512], gA + r0);
    async_cp16(&Bs[bsel][w*1024],       gB + r0);
    async_cp16(&Bs[bsel][w*1024 + 512], gB + r0 + 16*1024);
  };

  stageF(0, 0);
  for (int kk = 0; kk < 32; kk++){
    int bsel = kk & 1;
    if (kk + 1 < 32){
      stageF(kk + 1, bsel ^ 1);
      asm volatile("s_waitcnt vmcnt(2)\n\ts_barrier" ::: "memory");
    } else {
      asm volatile("s_waitcnt vmcnt(0)\n\ts_barrier" ::: "memory");
    }
    bf16x8 af[2], bfr[2];
    #pragma unroll
    for (int si = 0; si < 2; si++)
      af[si] = *(const bf16x8*)&As[bsel][(16*si + lc)*32 + 8*lg];
    #pragma unroll
    for (int sj = 0; sj < 2; sj++)
      bfr[sj] = *(const bf16x8*)&Bs[bsel][(nj + 16*sj + lc)*32 + 8*lg];
    #pragma unroll
    for (int si = 0; si < 2; si++)
      #pragma unroll
      for (int sj = 0; sj < 2; sj++)
        acc[si][sj] = __builtin_amdgcn_mfma_f32_16x16x32_bf16(af[si], bfr[sj],
                                                              acc[si][sj], 0,0,0);
    asm volatile("s_barrier" ::: "memory");
  }

  float bv[2];
  #pragma unroll
  for (int sj = 0; sj < 2; sj++) bv[sj] = bu[nj + 16*sj + lc];
  #pragma unroll
  for (int si = 0; si < 2; si++)
    #pragma unroll
    for (int r = 0; r < 4; r++){
      int t = bt0 + 16*si + 4*lg + r;
      #pragma unroll
      for (int sj = 0; sj < 2; sj++)
        out[(size_t)t*128 + nj + 16*sj + lc] = silu_f(acc[si][sj][r] + bv[sj]);
    }
}

// ---------------------------------------------------------------------------
extern "C" void kernel_launch(void* const* d_in, const int* in_sizes, int n_in,
                              void* d_out, int out_size, void* d_ws, size_t ws_size,
                              hipStream_t stream) {
  const float* x  = (const float*)d_in[0];
  const float* Wq = (const float*)d_in[1];
  const float* bq = (const float*)d_in[2];
  const float* Wk = (const float*)d_in[3];
  const float* bk = (const float*)d_in[4];
  const float* Wv = (const float*)d_in[5];
  const float* Wu = (const float*)d_in[6];
  const float* bu = (const float*)d_in[7];
  float* out = (float*)d_out;

  // Workspace layout (generous slack; Xpad is 2,105,344 B)
  char* ws = (char*)d_ws;
  ushort_t* Q2   = (ushort_t*)(ws + 0);            // 16 MB
  ushort_t* K2   = (ushort_t*)(ws + 16777216);     // 16 MB
  ushort_t* V2t  = (ushort_t*)(ws + 33554432);     // 16 MB
  ushort_t* O2   = (ushort_t*)(ws + 50331648);     // 16 MB (bf16 [8192][1024])
  ushort_t* Xpad = (ushort_t*)(ws + 67108864);     // 2.008 MB
  ushort_t* W2p  = (ushort_t*)(ws + 70254592);     // 2.5 MB
  ushort_t* Wvp  = (ushort_t*)(ws + 73400320);     // 0.25 MB
  ushort_t* Wub  = (ushort_t*)(ws + 74448896);     // 0.25 MB

  prep<<<dim3(4228, 1, 1), 256, 0, stream>>>(Wq, Wk, Wv, Wu, x,
                                             W2p, Wvp, Wub, Xpad);

  gemm_qkv<<<dim3(24, 64, 1), 256, 0, stream>>>(Xpad, W2p, Wvp, bq, bk,
                                                Q2, K2, V2t);

  attn<<<dim3(512, 1, 1), 256, 0, stream>>>(Q2, K2, V2t, O2);
  finalmm<<<dim3(256, 1, 1), 256, 0, stream>>>(O2, Wub, bu, out);
}

// Round 5
// 206.023 us; speedup vs baseline: 1.3646x; 1.0082x over previous
//
#include <hip/hip_runtime.h>
#include <hip/hip_bf16.h>
#include <stdint.h>

// B=4, T=2048, K(=D)=128, H=8, KS=5, DIL=2, PAD=8, M=B*H=32
// scale = 128^0.25 ; inv = 0.29730177875068026

typedef __attribute__((ext_vector_type(8))) short bf16x8;
typedef __attribute__((ext_vector_type(4))) float f32x4;
typedef __attribute__((ext_vector_type(4))) int   i32x4;
typedef unsigned short ushort_t;

__device__ __forceinline__ unsigned short f2bf(float x){
  union{float f; unsigned u;} v; v.f = x;
  unsigned r = v.u + 0x7FFFu + ((v.u >> 16) & 1u);   // RNE
  return (unsigned short)(r >> 16);
}
__device__ __forceinline__ float silu_f(float x){ return x / (1.f + __expf(-x)); }

__device__ __forceinline__ int cvt_pk_bf16(float lo, float hi){
  int r;
  asm("v_cvt_pk_bf16_f32 %0, %1, %2" : "=v"(r) : "v"(lo), "v"(hi));
  return r;
}

__device__ __forceinline__ void async_cp16(void* lds, const void* g){
  __builtin_amdgcn_global_load_lds(
      (const __attribute__((address_space(1))) unsigned int*)g,
      (__attribute__((address_space(3))) unsigned int*)lds, 16, 0, 0);
}

// ---------------------------------------------------------------------------
// prep v2: coalesced + vectorized.  (unchanged, R0 baseline)
// ---------------------------------------------------------------------------
__global__ __launch_bounds__(256) void prep(const float* __restrict__ Wq,
                                            const float* __restrict__ Wk,
                                            const float* __restrict__ Wv,
                                            const float* __restrict__ Wu,
                                            const float* __restrict__ x,
                                            ushort_t* __restrict__ W2p,
                                            ushort_t* __restrict__ Wvp,
                                            ushort_t* __restrict__ Wub,
                                            ushort_t* __restrict__ Xpad){
  __shared__ float row[640];
  int n = blockIdx.x;
  int tid = threadIdx.x;
  if (n < 2048){
    int qk = n >> 10, h = (n >> 7) & 7, d = n & 127;
    const float* src = (qk ? Wk : Wq) + (size_t)(d*8 + h)*640;
    if (tid < 160) *(float4*)&row[tid*4] = *(const float4*)&src[tid*4];
    __syncthreads();
    for (int rp = tid; rp < 640; rp += 256){
      int j = rp >> 7, ci = rp & 127;
      W2p[(size_t)n*640 + rp] = f2bf(row[ci*5 + j]);
    }
  } else if (n < 3072){
    int co = n - 2048;
    if (tid < 32){
      float4 v = *(const float4*)&Wv[(size_t)co*128 + tid*4];
      uint2 pv;
      pv.x = (unsigned)cvt_pk_bf16(v.x, v.y);
      pv.y = (unsigned)cvt_pk_bf16(v.z, v.w);
      *(uint2*)&Wvp[(size_t)co*128 + tid*4] = pv;
    }
  } else if (n < 3200){
    int j = n - 3072;
    float4 v = *(const float4*)&Wu[(size_t)j*1024 + tid*4];
    uint2 pv;
    pv.x = (unsigned)cvt_pk_bf16(v.x, v.y);
    pv.y = (unsigned)cvt_pk_bf16(v.z, v.w);
    *(uint2*)&Wub[(size_t)j*1024 + tid*4] = pv;
  } else {
    int idx = n - 3200;              // 0..1027 ; 257 blocks per batch (2056=8*257)
    int b = idx / 257, rblk = idx - b*257;
    int rt = rblk*8 + (tid >> 5);
    int ci4 = (tid & 31) * 4;
    int t = rt - 8;
    uint2 val; val.x = 0u; val.y = 0u;
    if (t >= 0){
      float4 v = *(const float4*)&x[((size_t)(b*2048 + t))*128 + ci4];
      val.x = (unsigned)cvt_pk_bf16(v.x, v.y);
      val.y = (unsigned)cvt_pk_bf16(v.z, v.w);
    }
    *(uint2*)&Xpad[((size_t)(b*2056 + rt))*128 + ci4] = val;
  }
}

// ---------------------------------------------------------------------------
// gemm_qkv (unchanged, R0 baseline): qk path dbuf vmcnt(4); v path dbuf vmcnt(4).
// ---------------------------------------------------------------------------
__global__ __launch_bounds__(256) void gemm_qkv(
    const ushort_t* __restrict__ Xpad,  // [4][2056][128]
    const ushort_t* __restrict__ W2p,   // [2048][640]
    const ushort_t* __restrict__ Wvp,   // [1024][128]
    const float* __restrict__ bq, const float* __restrict__ bk,
    ushort_t* __restrict__ Q2, ushort_t* __restrict__ K2,
    ushort_t* __restrict__ V2t)
{
  __shared__ ushort_t As[2][128*32] __attribute__((aligned(16)));
  __shared__ ushort_t Bs[2][128*32] __attribute__((aligned(16)));
  int bt0 = blockIdx.y * 128;
  int tid = threadIdx.x;
  int w = tid >> 6, ln = tid & 63;
  int lc = ln & 15, lg = ln >> 4;
  int mi = (w & 1) * 64, nj = (w >> 1) * 64;
  int srow = ln >> 2;
  int kseg = (ln & 3) * 8;
  int b = bt0 >> 11, tl0 = bt0 & 2047;

  f32x4 acc[4][4];
  #pragma unroll
  for (int si = 0; si < 4; si++)
    #pragma unroll
    for (int sj = 0; sj < 4; sj++) acc[si][sj] = (f32x4){0.f,0.f,0.f,0.f};

  if (blockIdx.x < 16){
    int n0 = blockIdx.x * 128;
    const ushort_t* gA = Xpad + (size_t)(b*2056 + tl0 + w*32 + srow)*128 + kseg;
    const ushort_t* gB = W2p + (size_t)(n0  + w*32 + srow)*640 + kseg;

    auto stageAB = [&](int kk, int bsel){
      int j = kk >> 2, ci0 = (kk & 3) * 32;
      int r0 = kk * 32;
      const ushort_t* a0 = gA + (size_t)(2*j)*128 + ci0;
      async_cp16(&As[bsel][w*1024],       a0);
      async_cp16(&As[bsel][w*1024 + 512], a0 + 16*128);
      async_cp16(&Bs[bsel][w*1024],       gB + r0);
      async_cp16(&Bs[bsel][w*1024 + 512], gB + r0 + 16*640);
    };

    stageAB(0, 0);
    for (int kk = 0; kk < 20; kk++){
      int bsel = kk & 1;
      if (kk + 1 < 20){
        stageAB(kk + 1, bsel ^ 1);
        asm volatile("s_waitcnt vmcnt(4)\n\ts_barrier" ::: "memory");
      } else {
        asm volatile("s_waitcnt vmcnt(0)\n\ts_barrier" ::: "memory");
      }
      bf16x8 af[4], bfr[4];
      #pragma unroll
      for (int si = 0; si < 4; si++)
        af[si] = *(const bf16x8*)&As[bsel][(mi + 16*si + lc)*32 + 8*lg];
      #pragma unroll
      for (int sj = 0; sj < 4; sj++)
        bfr[sj] = *(const bf16x8*)&Bs[bsel][(nj + 16*sj + lc)*32 + 8*lg];
      #pragma unroll
      for (int si = 0; si < 4; si++)
        #pragma unroll
        for (int sj = 0; sj < 4; sj++)
          acc[si][sj] = __builtin_amdgcn_mfma_f32_16x16x32_bf16(af[si], bfr[sj],
                                                                acc[si][sj], 0,0,0);
      asm volatile("s_barrier" ::: "memory");
    }

    const float inv_scale = 0.29730177875068026f;
    int qk = n0 >> 10, h = (n0 >> 7) & 7;
    const float* bias = qk ? bk : bq;
    ushort_t* dst = qk ? K2 : Q2;
    float bv[4];
    #pragma unroll
    for (int sj = 0; sj < 4; sj++) bv[sj] = bias[(nj + 16*sj + lc)*8 + h];

    #pragma unroll
    for (int si = 0; si < 4; si++){
      int btb = bt0 + mi + 16*si + 4*lg;
      #pragma unroll
      for (int r = 0; r < 4; r++){
        int t = btb + r;
        int bb = t >> 11, tl = t & 2047;
        size_t rowoff = ((size_t)(bb*8 + (tl >> 8))*2048 + (tl & 255)*8 + h)*128;
        #pragma unroll
        for (int sj = 0; sj < 4; sj++){
          int d = nj + 16*sj + lc;
          dst[rowoff + d] = f2bf(silu_f(acc[si][sj][r] + bv[sj]) * inv_scale);
        }
      }
    }
  } else {
    int n0 = (blockIdx.x - 16) * 128;
    const ushort_t* gA = Xpad + (size_t)(b*2056 + 8 + tl0 + w*32 + srow)*128 + kseg;
    const ushort_t* gB = Wvp  + (size_t)(n0 + w*32 + srow)*128 + kseg;

    auto stageV = [&](int kk, int bsel){
      int r0 = kk * 32;
      async_cp16(&As[bsel][w*1024],       gA + r0);
      async_cp16(&As[bsel][w*1024 + 512], gA + r0 + 16*128);
      async_cp16(&Bs[bsel][w*1024],       gB + r0);
      async_cp16(&Bs[bsel][w*1024 + 512], gB + r0 + 16*128);
    };

    stageV(0, 0);
    for (int kk = 0; kk < 4; kk++){
      int bsel = kk & 1;
      if (kk + 1 < 4){
        stageV(kk + 1, bsel ^ 1);
        asm volatile("s_waitcnt vmcnt(4)\n\ts_barrier" ::: "memory");
      } else {
        asm volatile("s_waitcnt vmcnt(0)\n\ts_barrier" ::: "memory");
      }
      bf16x8 af[4], bfr[4];
      #pragma unroll
      for (int si = 0; si < 4; si++)
        af[si] = *(const bf16x8*)&As[bsel][(mi + 16*si + lc)*32 + 8*lg];
      #pragma unroll
      for (int sj = 0; sj < 4; sj++)
        bfr[sj] = *(const bf16x8*)&Bs[bsel][(nj + 16*sj + lc)*32 + 8*lg];
      #pragma unroll
      for (int si = 0; si < 4; si++)
        #pragma unroll
        for (int sj = 0; sj < 4; sj++)
          acc[si][sj] = __builtin_amdgcn_mfma_f32_16x16x32_bf16(af[si], bfr[sj],
                                                                acc[si][sj], 0,0,0);
      asm volatile("s_barrier" ::: "memory");
    }

    #pragma unroll
    for (int si = 0; si < 4; si++){
      int btb = bt0 + mi + 16*si + 4*lg;
      #pragma unroll
      for (int r = 0; r < 4; r++){
        int t = btb + r;
        int bb = t >> 11, tl = t & 2047;
        int mm = bb*8 + (tl >> 8);
        int tpb = (tl & 255)*8;
        #pragma unroll
        for (int sj = 0; sj < 4; sj++){
          int co = n0 + nj + 16*sj + lc;
          int d = co >> 3, hh = co & 7;
          V2t[((size_t)mm*128 + d)*2048 + tpb + hh] = f2bf(silu_f(acc[si][sj][r]));
        }
      }
    }
  }
}

// ---------------------------------------------------------------------------
// Flash attention — EXACT round-8/10/13/14 kernel (passed 4x, 84us). FROZEN.
// No setprio (R3: -6%), no dual-tile (R1), no V-destage (R2), no 8-wave (R4).
// ---------------------------------------------------------------------------
__global__ __launch_bounds__(256) void attn(
    const ushort_t* __restrict__ Q2,   // [32][2048][128]
    const ushort_t* __restrict__ K2,   // [32][2048][128]
    const ushort_t* __restrict__ V2t,  // [32][128][2048]
    ushort_t* __restrict__ O2)         // [8192][1024] bf16
{
  __shared__ i32x4 kbuf[2][1024];      // [buf][(st*4+c)*64 + lane]  16KB each
  __shared__ i32x4 vbuf[2][1024];      // [buf][(dt*2+ks)*64 + lane] 16KB each

  int bid = blockIdx.x;                      // 512 blocks
  int m   = ((bid & 7) << 2) | ((bid >> 3) & 3);  // XCD-L2 locality swizzle
  int ip  = bid >> 5;                        // pair index 0..15
  int tid = threadIdx.x;
  int w = tid >> 6, l = tid & 63;
  int lc = l & 15, lg = l >> 4;

  int iA = 31 - ip, iB = ip;
  int ntA = iA + 1;
  const int nt = 33;

  const size_t mQ = (size_t)m * 2048;
  const ushort_t* Kbase = K2  + mQ * 128;
  const ushort_t* Vbase = V2t + (size_t)m * 128 * 2048;
  int hb = m & 7, bI = m >> 3;

  int psel[4];
  #pragma unroll
  for (int w2 = 0; w2 < 4; w2++)
    psel[w2] = ((((2*(lg & 1) + (w2 >> 1)) << 4) | lc) << 2);

  auto stage = [&](int s0, int bsel){
    const ushort_t* krow = Kbase + (size_t)(s0 + w*16 + lc)*128 + 8*lg;
    #pragma unroll
    for (int c = 0; c < 4; c++)
      async_cp16(&kbuf[bsel][(w*4 + c)*64], krow + 32*c);
    #pragma unroll
    for (int j = 0; j < 4; j++){
      int dt = w*2 + (j >> 1);
      const ushort_t* vrow = Vbase + (size_t)(dt*16 + lc)*2048
                             + s0 + (j & 1)*32 + 8*lg;
      async_cp16(&vbuf[bsel][(w*4 + j)*64], vrow);
    }
  };

  int qb = iA*64 + w*16;
  bf16x8 qfrag[4];
  {
    const ushort_t* qp = Q2 + (mQ + qb + lc)*128 + 8*lg;
    #pragma unroll
    for (int c = 0; c < 4; c++) qfrag[c] = *(const bf16x8*)(qp + 32*c);
  }
  f32x4 oacc[8];
  #pragma unroll
  for (int dt = 0; dt < 8; dt++) oacc[dt] = (f32x4){0.f,0.f,0.f,0.f};
  float lrow = 0.f;

  const float LOG2E = 1.4426950408889634f;
  const float EOFF  = -11.541560327111707f;   // -8 * log2(e)

  stage(0, 0);

  for (int step = 0; step < nt; step++){
    if (step == ntA){
      float lt = lrow;
      lt += __shfl_xor(lt, 16);
      lt += __shfl_xor(lt, 32);
      float invl = 1.f / lt;
      size_t obase = ((size_t)(bI*2048 + qb + lc))*1024 + hb*128 + 4*lg;
      #pragma unroll
      for (int dt = 0; dt < 8; dt++){
        uint2 val;
        val.x = (unsigned)cvt_pk_bf16(oacc[dt][0]*invl, oacc[dt][1]*invl);
        val.y = (unsigned)cvt_pk_bf16(oacc[dt][2]*invl, oacc[dt][3]*invl);
        *(uint2*)&O2[obase + 16*dt] = val;
      }
      qb = iB*64 + w*16;
      const ushort_t* qp = Q2 + (mQ + qb + lc)*128 + 8*lg;
      #pragma unroll
      for (int c = 0; c < 4; c++) qfrag[c] = *(const bf16x8*)(qp + 32*c);
      #pragma unroll
      for (int dt = 0; dt < 8; dt++) oacc[dt] = (f32x4){0.f,0.f,0.f,0.f};
      lrow = 0.f;
    }
    int local = (step < ntA) ? step : step - ntA;
    bool isLast = (step == ntA - 1) || (step == nt - 1);
    int s0 = local * 64;
    int bsel = step & 1;

    if (step + 1 < nt){
      int nl = (step + 1 < ntA) ? step + 1 : step + 1 - ntA;
      stage(nl*64, bsel ^ 1);
      asm volatile("s_waitcnt vmcnt(8)\n\ts_barrier" ::: "memory");
    } else {
      asm volatile("s_waitcnt vmcnt(0)\n\ts_barrier" ::: "memory");
    }

    f32x4 sacc[4];
    #pragma unroll
    for (int st = 0; st < 4; st++){
      f32x4 a2 = (f32x4){0.f,0.f,0.f,0.f};
      #pragma unroll
      for (int c = 0; c < 4; c++){
        bf16x8 kf = *(bf16x8*)&kbuf[bsel][(st*4 + c)*64 + l];
        a2 = __builtin_amdgcn_mfma_f32_16x16x32_bf16(kf, qfrag[c], a2, 0, 0, 0);
      }
      sacc[st] = a2;
    }
    if (isLast){
      int qg = qb + lc;
      #pragma unroll
      for (int st = 0; st < 4; st++)
        #pragma unroll
        for (int r = 0; r < 4; r++){
          int sg = s0 + st*16 + 4*lg + r;
          if (sg > qg) sacc[st][r] = -1e30f;
        }
    }

    float p_[4][4];
    #pragma unroll
    for (int st = 0; st < 4; st++)
      #pragma unroll
      for (int r = 0; r < 4; r++){
        float sv = fminf(fmaf(sacc[st][r], LOG2E, EOFF), 108.f);
        float pv = __builtin_amdgcn_exp2f(sv);
        p_[st][r] = pv;
        lrow += pv;
      }

    #pragma unroll
    for (int ks = 0; ks < 2; ks++){
      int pk0[2], pk1[2];
      #pragma unroll
      for (int pa = 0; pa < 2; pa++){
        pk0[pa] = cvt_pk_bf16(p_[2*ks][2*pa],   p_[2*ks][2*pa+1]);
        pk1[pa] = cvt_pk_bf16(p_[2*ks+1][2*pa], p_[2*ks+1][2*pa+1]);
      }
      union { int i[4]; bf16x8 v; } bfr;
      #pragma unroll
      for (int w2 = 0; w2 < 4; w2++){
        int v0 = __builtin_amdgcn_ds_bpermute(psel[w2], pk0[w2 & 1]);
        int v1 = __builtin_amdgcn_ds_bpermute(psel[w2], pk1[w2 & 1]);
        bfr.i[w2] = (lg >> 1) ? v1 : v0;
      }
      #pragma unroll
      for (int dt = 0; dt < 8; dt++){
        bf16x8 vf = *(bf16x8*)&vbuf[bsel][(dt*2 + ks)*64 + l];
        oacc[dt] = __builtin_amdgcn_mfma_f32_16x16x32_bf16(vf, bfr.v, oacc[dt], 0, 0, 0);
      }
    }
    asm volatile("s_barrier" ::: "memory");
  }

  float lt = lrow;
  lt += __shfl_xor(lt, 16);
  lt += __shfl_xor(lt, 32);
  float invl = 1.f / lt;
  size_t obase = ((size_t)(bI*2048 + qb + lc))*1024 + hb*128 + 4*lg;
  #pragma unroll
  for (int dt = 0; dt < 8; dt++){
    uint2 val;
    val.x = (unsigned)cvt_pk_bf16(oacc[dt][0]*invl, oacc[dt][1]*invl);
    val.y = (unsigned)cvt_pk_bf16(oacc[dt][2]*invl, oacc[dt][3]*invl);
    *(uint2*)&O2[obase + 16*dt] = val;
  }
}

// ---------------------------------------------------------------------------
// finalmm v2: 16-row M-tiles -> 512 blocks = 2 blocks/CU (was 256 = 1/CU,
// 1 wave/SIMD). Doubles block-level overlap of the latency-bound 32-iter
// K-loop. Staging keeps the proven {As wave0, Bs all waves, vmcnt(2)}
// semantics; As is 16x32 (one cp16), per-wave acc[1][2].
// ---------------------------------------------------------------------------
__global__ __launch_bounds__(256) void finalmm(
    const ushort_t* __restrict__ O2,    // [8192][1024] bf16
    const ushort_t* __restrict__ Wub,   // [128][1024] bf16
    const float* __restrict__ bu,
    float* __restrict__ out)            // [8192][128]
{
  __shared__ ushort_t As[2][16*32]  __attribute__((aligned(16)));   // 2x1 KB
  __shared__ ushort_t Bs[2][128*32] __attribute__((aligned(16)));   // 2x8 KB
  int bt0 = blockIdx.x * 16;
  int tid = threadIdx.x;
  int w = tid >> 6, ln = tid & 63;
  int lc = ln & 15, lg = ln >> 4;
  int nj = w * 32;
  int srow = ln >> 2;
  int kseg = (ln & 3) * 8;

  f32x4 acc[2];
  #pragma unroll
  for (int sj = 0; sj < 2; sj++) acc[sj] = (f32x4){0.f,0.f,0.f,0.f};

  const ushort_t* gA = O2  + (size_t)(bt0 + srow)*1024 + kseg;
  const ushort_t* gB = Wub + (size_t)(w*32 + srow)*1024 + kseg;

  auto stageF = [&](int kk, int bsel){
    int r0 = kk * 32;
    if (w == 0) async_cp16(&As[bsel][0], gA + r0);
    async_cp16(&Bs[bsel][w*1024],       gB + r0);
    async_cp16(&Bs[bsel][w*1024 + 512], gB + r0 + 16*1024);
  };

  stageF(0, 0);
  for (int kk = 0; kk < 32; kk++){
    int bsel = kk & 1;
    if (kk + 1 < 32){
      stageF(kk + 1, bsel ^ 1);
      asm volatile("s_waitcnt vmcnt(2)\n\ts_barrier" ::: "memory");
    } else {
      asm volatile("s_waitcnt vmcnt(0)\n\ts_barrier" ::: "memory");
    }
    bf16x8 af, bfr[2];
    af = *(const bf16x8*)&As[bsel][(lc)*32 + 8*lg];
    #pragma unroll
    for (int sj = 0; sj < 2; sj++)
      bfr[sj] = *(const bf16x8*)&Bs[bsel][(nj + 16*sj + lc)*32 + 8*lg];
    #pragma unroll
    for (int sj = 0; sj < 2; sj++)
      acc[sj] = __builtin_amdgcn_mfma_f32_16x16x32_bf16(af, bfr[sj],
                                                        acc[sj], 0,0,0);
    asm volatile("s_barrier" ::: "memory");
  }

  float bv[2];
  #pragma unroll
  for (int sj = 0; sj < 2; sj++) bv[sj] = bu[nj + 16*sj + lc];
  #pragma unroll
  for (int r = 0; r < 4; r++){
    int t = bt0 + 4*lg + r;
    #pragma unroll
    for (int sj = 0; sj < 2; sj++)
      out[(size_t)t*128 + nj + 16*sj + lc] = silu_f(acc[sj][r] + bv[sj]);
  }
}

// ---------------------------------------------------------------------------
extern "C" void kernel_launch(void* const* d_in, const int* in_sizes, int n_in,
                              void* d_out, int out_size, void* d_ws, size_t ws_size,
                              hipStream_t stream) {
  const float* x  = (const float*)d_in[0];
  const float* Wq = (const float*)d_in[1];
  const float* bq = (const float*)d_in[2];
  const float* Wk = (const float*)d_in[3];
  const float* bk = (const float*)d_in[4];
  const float* Wv = (const float*)d_in[5];
  const float* Wu = (const float*)d_in[6];
  const float* bu = (const float*)d_in[7];
  float* out = (float*)d_out;

  // Workspace layout (generous slack; Xpad is 2,105,344 B)
  char* ws = (char*)d_ws;
  ushort_t* Q2   = (ushort_t*)(ws + 0);            // 16 MB
  ushort_t* K2   = (ushort_t*)(ws + 16777216);     // 16 MB
  ushort_t* V2t  = (ushort_t*)(ws + 33554432);     // 16 MB
  ushort_t* O2   = (ushort_t*)(ws + 50331648);     // 16 MB (bf16 [8192][1024])
  ushort_t* Xpad = (ushort_t*)(ws + 67108864);     // 2.008 MB
  ushort_t* W2p  = (ushort_t*)(ws + 70254592);     // 2.5 MB
  ushort_t* Wvp  = (ushort_t*)(ws + 73400320);     // 0.25 MB
  ushort_t* Wub  = (ushort_t*)(ws + 74448896);     // 0.25 MB

  prep<<<dim3(4228, 1, 1), 256, 0, stream>>>(Wq, Wk, Wv, Wu, x,
                                             W2p, Wvp, Wub, Xpad);

  gemm_qkv<<<dim3(24, 64, 1), 256, 0, stream>>>(Xpad, W2p, Wvp, bq, bk,
                                                Q2, K2, V2t);

  attn<<<dim3(512, 1, 1), 256, 0, stream>>>(Q2, K2, V2t, O2);
  finalmm<<<dim3(512, 1, 1), 256, 0, stream>>>(O2, Wub, bu, out);
}

// Round 6
// 201.879 us; speedup vs baseline: 1.3926x; 1.0205x over previous
//
#include <hip/hip_runtime.h>
#include <hip/hip_bf16.h>
#include <stdint.h>

// B=4, T=2048, K(=D)=128, H=8, KS=5, DIL=2, PAD=8, M=B*H=32
// scale = 128^0.25 ; inv = 0.29730177875068026

typedef __attribute__((ext_vector_type(8))) short bf16x8;
typedef __attribute__((ext_vector_type(4))) float f32x4;
typedef __attribute__((ext_vector_type(4))) int   i32x4;
typedef unsigned short ushort_t;

__device__ __forceinline__ unsigned short f2bf(float x){
  union{float f; unsigned u;} v; v.f = x;
  unsigned r = v.u + 0x7FFFu + ((v.u >> 16) & 1u);   // RNE
  return (unsigned short)(r >> 16);
}
__device__ __forceinline__ float silu_f(float x){ return x / (1.f + __expf(-x)); }

__device__ __forceinline__ int cvt_pk_bf16(float lo, float hi){
  int r;
  asm("v_cvt_pk_bf16_f32 %0, %1, %2" : "=v"(r) : "v"(lo), "v"(hi));
  return r;
}

// VALU cross-lane swaps (gfx950). After p32: a=[a.l0-31|b.l0-31], b=[a.l32-63|b.l32-63].
// After p16: a=[a.r0|b.r0|a.r2|b.r2], b=[a.r1|b.r1|a.r3|b.r3]  (rows of 16 lanes).
__device__ __forceinline__ void permlane32_swap(int &a, int &b){
  asm volatile("v_permlane32_swap_b32 %0, %1" : "+v"(a), "+v"(b));
}
__device__ __forceinline__ void permlane16_swap(int &a, int &b){
  asm volatile("v_permlane16_swap_b32 %0, %1" : "+v"(a), "+v"(b));
}

__device__ __forceinline__ void async_cp16(void* lds, const void* g){
  __builtin_amdgcn_global_load_lds(
      (const __attribute__((address_space(1))) unsigned int*)g,
      (__attribute__((address_space(3))) unsigned int*)lds, 16, 0, 0);
}

// ---------------------------------------------------------------------------
// prep v2: coalesced + vectorized.  (unchanged, R0 baseline)
// ---------------------------------------------------------------------------
__global__ __launch_bounds__(256) void prep(const float* __restrict__ Wq,
                                            const float* __restrict__ Wk,
                                            const float* __restrict__ Wv,
                                            const float* __restrict__ Wu,
                                            const float* __restrict__ x,
                                            ushort_t* __restrict__ W2p,
                                            ushort_t* __restrict__ Wvp,
                                            ushort_t* __restrict__ Wub,
                                            ushort_t* __restrict__ Xpad){
  __shared__ float row[640];
  int n = blockIdx.x;
  int tid = threadIdx.x;
  if (n < 2048){
    int qk = n >> 10, h = (n >> 7) & 7, d = n & 127;
    const float* src = (qk ? Wk : Wq) + (size_t)(d*8 + h)*640;
    if (tid < 160) *(float4*)&row[tid*4] = *(const float4*)&src[tid*4];
    __syncthreads();
    for (int rp = tid; rp < 640; rp += 256){
      int j = rp >> 7, ci = rp & 127;
      W2p[(size_t)n*640 + rp] = f2bf(row[ci*5 + j]);
    }
  } else if (n < 3072){
    int co = n - 2048;
    if (tid < 32){
      float4 v = *(const float4*)&Wv[(size_t)co*128 + tid*4];
      uint2 pv;
      pv.x = (unsigned)cvt_pk_bf16(v.x, v.y);
      pv.y = (unsigned)cvt_pk_bf16(v.z, v.w);
      *(uint2*)&Wvp[(size_t)co*128 + tid*4] = pv;
    }
  } else if (n < 3200){
    int j = n - 3072;
    float4 v = *(const float4*)&Wu[(size_t)j*1024 + tid*4];
    uint2 pv;
    pv.x = (unsigned)cvt_pk_bf16(v.x, v.y);
    pv.y = (unsigned)cvt_pk_bf16(v.z, v.w);
    *(uint2*)&Wub[(size_t)j*1024 + tid*4] = pv;
  } else {
    int idx = n - 3200;              // 0..1027 ; 257 blocks per batch (2056=8*257)
    int b = idx / 257, rblk = idx - b*257;
    int rt = rblk*8 + (tid >> 5);
    int ci4 = (tid & 31) * 4;
    int t = rt - 8;
    uint2 val; val.x = 0u; val.y = 0u;
    if (t >= 0){
      float4 v = *(const float4*)&x[((size_t)(b*2048 + t))*128 + ci4];
      val.x = (unsigned)cvt_pk_bf16(v.x, v.y);
      val.y = (unsigned)cvt_pk_bf16(v.z, v.w);
    }
    *(uint2*)&Xpad[((size_t)(b*2056 + rt))*128 + ci4] = val;
  }
}

// ---------------------------------------------------------------------------
// gemm_qkv (unchanged, R0 baseline): qk path dbuf vmcnt(4); v path dbuf vmcnt(4).
// ---------------------------------------------------------------------------
__global__ __launch_bounds__(256) void gemm_qkv(
    const ushort_t* __restrict__ Xpad,  // [4][2056][128]
    const ushort_t* __restrict__ W2p,   // [2048][640]
    const ushort_t* __restrict__ Wvp,   // [1024][128]
    const float* __restrict__ bq, const float* __restrict__ bk,
    ushort_t* __restrict__ Q2, ushort_t* __restrict__ K2,
    ushort_t* __restrict__ V2t)
{
  __shared__ ushort_t As[2][128*32] __attribute__((aligned(16)));
  __shared__ ushort_t Bs[2][128*32] __attribute__((aligned(16)));
  int bt0 = blockIdx.y * 128;
  int tid = threadIdx.x;
  int w = tid >> 6, ln = tid & 63;
  int lc = ln & 15, lg = ln >> 4;
  int mi = (w & 1) * 64, nj = (w >> 1) * 64;
  int srow = ln >> 2;
  int kseg = (ln & 3) * 8;
  int b = bt0 >> 11, tl0 = bt0 & 2047;

  f32x4 acc[4][4];
  #pragma unroll
  for (int si = 0; si < 4; si++)
    #pragma unroll
    for (int sj = 0; sj < 4; sj++) acc[si][sj] = (f32x4){0.f,0.f,0.f,0.f};

  if (blockIdx.x < 16){
    int n0 = blockIdx.x * 128;
    const ushort_t* gA = Xpad + (size_t)(b*2056 + tl0 + w*32 + srow)*128 + kseg;
    const ushort_t* gB = W2p + (size_t)(n0  + w*32 + srow)*640 + kseg;

    auto stageAB = [&](int kk, int bsel){
      int j = kk >> 2, ci0 = (kk & 3) * 32;
      int r0 = kk * 32;
      const ushort_t* a0 = gA + (size_t)(2*j)*128 + ci0;
      async_cp16(&As[bsel][w*1024],       a0);
      async_cp16(&As[bsel][w*1024 + 512], a0 + 16*128);
      async_cp16(&Bs[bsel][w*1024],       gB + r0);
      async_cp16(&Bs[bsel][w*1024 + 512], gB + r0 + 16*640);
    };

    stageAB(0, 0);
    for (int kk = 0; kk < 20; kk++){
      int bsel = kk & 1;
      if (kk + 1 < 20){
        stageAB(kk + 1, bsel ^ 1);
        asm volatile("s_waitcnt vmcnt(4)\n\ts_barrier" ::: "memory");
      } else {
        asm volatile("s_waitcnt vmcnt(0)\n\ts_barrier" ::: "memory");
      }
      bf16x8 af[4], bfr[4];
      #pragma unroll
      for (int si = 0; si < 4; si++)
        af[si] = *(const bf16x8*)&As[bsel][(mi + 16*si + lc)*32 + 8*lg];
      #pragma unroll
      for (int sj = 0; sj < 4; sj++)
        bfr[sj] = *(const bf16x8*)&Bs[bsel][(nj + 16*sj + lc)*32 + 8*lg];
      #pragma unroll
      for (int si = 0; si < 4; si++)
        #pragma unroll
        for (int sj = 0; sj < 4; sj++)
          acc[si][sj] = __builtin_amdgcn_mfma_f32_16x16x32_bf16(af[si], bfr[sj],
                                                                acc[si][sj], 0,0,0);
      asm volatile("s_barrier" ::: "memory");
    }

    const float inv_scale = 0.29730177875068026f;
    int qk = n0 >> 10, h = (n0 >> 7) & 7;
    const float* bias = qk ? bk : bq;
    ushort_t* dst = qk ? K2 : Q2;
    float bv[4];
    #pragma unroll
    for (int sj = 0; sj < 4; sj++) bv[sj] = bias[(nj + 16*sj + lc)*8 + h];

    #pragma unroll
    for (int si = 0; si < 4; si++){
      int btb = bt0 + mi + 16*si + 4*lg;
      #pragma unroll
      for (int r = 0; r < 4; r++){
        int t = btb + r;
        int bb = t >> 11, tl = t & 2047;
        size_t rowoff = ((size_t)(bb*8 + (tl >> 8))*2048 + (tl & 255)*8 + h)*128;
        #pragma unroll
        for (int sj = 0; sj < 4; sj++){
          int d = nj + 16*sj + lc;
          dst[rowoff + d] = f2bf(silu_f(acc[si][sj][r] + bv[sj]) * inv_scale);
        }
      }
    }
  } else {
    int n0 = (blockIdx.x - 16) * 128;
    const ushort_t* gA = Xpad + (size_t)(b*2056 + 8 + tl0 + w*32 + srow)*128 + kseg;
    const ushort_t* gB = Wvp  + (size_t)(n0 + w*32 + srow)*128 + kseg;

    auto stageV = [&](int kk, int bsel){
      int r0 = kk * 32;
      async_cp16(&As[bsel][w*1024],       gA + r0);
      async_cp16(&As[bsel][w*1024 + 512], gA + r0 + 16*128);
      async_cp16(&Bs[bsel][w*1024],       gB + r0);
      async_cp16(&Bs[bsel][w*1024 + 512], gB + r0 + 16*128);
    };

    stageV(0, 0);
    for (int kk = 0; kk < 4; kk++){
      int bsel = kk & 1;
      if (kk + 1 < 4){
        stageV(kk + 1, bsel ^ 1);
        asm volatile("s_waitcnt vmcnt(4)\n\ts_barrier" ::: "memory");
      } else {
        asm volatile("s_waitcnt vmcnt(0)\n\ts_barrier" ::: "memory");
      }
      bf16x8 af[4], bfr[4];
      #pragma unroll
      for (int si = 0; si < 4; si++)
        af[si] = *(const bf16x8*)&As[bsel][(mi + 16*si + lc)*32 + 8*lg];
      #pragma unroll
      for (int sj = 0; sj < 4; sj++)
        bfr[sj] = *(const bf16x8*)&Bs[bsel][(nj + 16*sj + lc)*32 + 8*lg];
      #pragma unroll
      for (int si = 0; si < 4; si++)
        #pragma unroll
        for (int sj = 0; sj < 4; sj++)
          acc[si][sj] = __builtin_amdgcn_mfma_f32_16x16x32_bf16(af[si], bfr[sj],
                                                                acc[si][sj], 0,0,0);
      asm volatile("s_barrier" ::: "memory");
    }

    #pragma unroll
    for (int si = 0; si < 4; si++){
      int btb = bt0 + mi + 16*si + 4*lg;
      #pragma unroll
      for (int r = 0; r < 4; r++){
        int t = btb + r;
        int bb = t >> 11, tl = t & 2047;
        int mm = bb*8 + (tl >> 8);
        int tpb = (tl & 255)*8;
        #pragma unroll
        for (int sj = 0; sj < 4; sj++){
          int co = n0 + nj + 16*sj + lc;
          int d = co >> 3, hh = co & 7;
          V2t[((size_t)mm*128 + d)*2048 + tpb + hh] = f2bf(silu_f(acc[si][sj][r]));
        }
      }
    }
  }
}

// ---------------------------------------------------------------------------
// Flash attention — frozen R0 structure with ONE change: the P-transpose
// (softmax fragments -> PV B-operand) moves off the contended LDS pipe.
// 16 ds_bpermute/wave/step  ->  8 VALU permlane swaps/wave/step:
//   (X,Y) = permlane32_swap(pk0[pa], pk1[pa])   ; X=[pk0.lo|pk1.lo] Y=[pk0.hi|pk1.hi]
//   (R0,R1) = permlane16_swap(X, Y)             ; R0=[X.r0|Y.r0|X.r2|Y.r2] etc.
//   bfr.i[pa]=R0, bfr.i[pa+2]=R1  == bpermute(psel[w2], pk_{lg>>1}[w2&1]) for all w2.
// (verified cell-by-cell against the original formula; psel deleted.)
// ---------------------------------------------------------------------------
__global__ __launch_bounds__(256) void attn(
    const ushort_t* __restrict__ Q2,   // [32][2048][128]
    const ushort_t* __restrict__ K2,   // [32][2048][128]
    const ushort_t* __restrict__ V2t,  // [32][128][2048]
    ushort_t* __restrict__ O2)         // [8192][1024] bf16
{
  __shared__ i32x4 kbuf[2][1024];      // [buf][(st*4+c)*64 + lane]  16KB each
  __shared__ i32x4 vbuf[2][1024];      // [buf][(dt*2+ks)*64 + lane] 16KB each

  int bid = blockIdx.x;                      // 512 blocks
  int m   = ((bid & 7) << 2) | ((bid >> 3) & 3);  // XCD-L2 locality swizzle
  int ip  = bid >> 5;                        // pair index 0..15
  int tid = threadIdx.x;
  int w = tid >> 6, l = tid & 63;
  int lc = l & 15, lg = l >> 4;

  int iA = 31 - ip, iB = ip;
  int ntA = iA + 1;
  const int nt = 33;

  const size_t mQ = (size_t)m * 2048;
  const ushort_t* Kbase = K2  + mQ * 128;
  const ushort_t* Vbase = V2t + (size_t)m * 128 * 2048;
  int hb = m & 7, bI = m >> 3;

  auto stage = [&](int s0, int bsel){
    const ushort_t* krow = Kbase + (size_t)(s0 + w*16 + lc)*128 + 8*lg;
    #pragma unroll
    for (int c = 0; c < 4; c++)
      async_cp16(&kbuf[bsel][(w*4 + c)*64], krow + 32*c);
    #pragma unroll
    for (int j = 0; j < 4; j++){
      int dt = w*2 + (j >> 1);
      const ushort_t* vrow = Vbase + (size_t)(dt*16 + lc)*2048
                             + s0 + (j & 1)*32 + 8*lg;
      async_cp16(&vbuf[bsel][(w*4 + j)*64], vrow);
    }
  };

  int qb = iA*64 + w*16;
  bf16x8 qfrag[4];
  {
    const ushort_t* qp = Q2 + (mQ + qb + lc)*128 + 8*lg;
    #pragma unroll
    for (int c = 0; c < 4; c++) qfrag[c] = *(const bf16x8*)(qp + 32*c);
  }
  f32x4 oacc[8];
  #pragma unroll
  for (int dt = 0; dt < 8; dt++) oacc[dt] = (f32x4){0.f,0.f,0.f,0.f};
  float lrow = 0.f;

  const float LOG2E = 1.4426950408889634f;
  const float EOFF  = -11.541560327111707f;   // -8 * log2(e)

  stage(0, 0);

  for (int step = 0; step < nt; step++){
    if (step == ntA){
      float lt = lrow;
      lt += __shfl_xor(lt, 16);
      lt += __shfl_xor(lt, 32);
      float invl = 1.f / lt;
      size_t obase = ((size_t)(bI*2048 + qb + lc))*1024 + hb*128 + 4*lg;
      #pragma unroll
      for (int dt = 0; dt < 8; dt++){
        uint2 val;
        val.x = (unsigned)cvt_pk_bf16(oacc[dt][0]*invl, oacc[dt][1]*invl);
        val.y = (unsigned)cvt_pk_bf16(oacc[dt][2]*invl, oacc[dt][3]*invl);
        *(uint2*)&O2[obase + 16*dt] = val;
      }
      qb = iB*64 + w*16;
      const ushort_t* qp = Q2 + (mQ + qb + lc)*128 + 8*lg;
      #pragma unroll
      for (int c = 0; c < 4; c++) qfrag[c] = *(const bf16x8*)(qp + 32*c);
      #pragma unroll
      for (int dt = 0; dt < 8; dt++) oacc[dt] = (f32x4){0.f,0.f,0.f,0.f};
      lrow = 0.f;
    }
    int local = (step < ntA) ? step : step - ntA;
    bool isLast = (step == ntA - 1) || (step == nt - 1);
    int s0 = local * 64;
    int bsel = step & 1;

    if (step + 1 < nt){
      int nl = (step + 1 < ntA) ? step + 1 : step + 1 - ntA;
      stage(nl*64, bsel ^ 1);
      asm volatile("s_waitcnt vmcnt(8)\n\ts_barrier" ::: "memory");
    } else {
      asm volatile("s_waitcnt vmcnt(0)\n\ts_barrier" ::: "memory");
    }

    f32x4 sacc[4];
    #pragma unroll
    for (int st = 0; st < 4; st++){
      f32x4 a2 = (f32x4){0.f,0.f,0.f,0.f};
      #pragma unroll
      for (int c = 0; c < 4; c++){
        bf16x8 kf = *(bf16x8*)&kbuf[bsel][(st*4 + c)*64 + l];
        a2 = __builtin_amdgcn_mfma_f32_16x16x32_bf16(kf, qfrag[c], a2, 0, 0, 0);
      }
      sacc[st] = a2;
    }
    if (isLast){
      int qg = qb + lc;
      #pragma unroll
      for (int st = 0; st < 4; st++)
        #pragma unroll
        for (int r = 0; r < 4; r++){
          int sg = s0 + st*16 + 4*lg + r;
          if (sg > qg) sacc[st][r] = -1e30f;
        }
    }

    float p_[4][4];
    #pragma unroll
    for (int st = 0; st < 4; st++)
      #pragma unroll
      for (int r = 0; r < 4; r++){
        float sv = fminf(fmaf(sacc[st][r], LOG2E, EOFF), 108.f);
        float pv = __builtin_amdgcn_exp2f(sv);
        p_[st][r] = pv;
        lrow += pv;
      }

    #pragma unroll
    for (int ks = 0; ks < 2; ks++){
      union { int i[4]; bf16x8 v; } bfr;
      #pragma unroll
      for (int pa = 0; pa < 2; pa++){
        int x = cvt_pk_bf16(p_[2*ks][2*pa],   p_[2*ks][2*pa+1]);   // pk0[pa]
        int y = cvt_pk_bf16(p_[2*ks+1][2*pa], p_[2*ks+1][2*pa+1]); // pk1[pa]
        permlane32_swap(x, y);   // x=[pk0.lo|pk1.lo]  y=[pk0.hi|pk1.hi]
        permlane16_swap(x, y);   // x -> words t=0, y -> words t=1
        bfr.i[pa]     = x;       // w2 = pa      (t=0)
        bfr.i[pa + 2] = y;       // w2 = pa + 2  (t=1)
      }
      #pragma unroll
      for (int dt = 0; dt < 8; dt++){
        bf16x8 vf = *(bf16x8*)&vbuf[bsel][(dt*2 + ks)*64 + l];
        oacc[dt] = __builtin_amdgcn_mfma_f32_16x16x32_bf16(vf, bfr.v, oacc[dt], 0, 0, 0);
      }
    }
    asm volatile("s_barrier" ::: "memory");
  }

  float lt = lrow;
  lt += __shfl_xor(lt, 16);
  lt += __shfl_xor(lt, 32);
  float invl = 1.f / lt;
  size_t obase = ((size_t)(bI*2048 + qb + lc))*1024 + hb*128 + 4*lg;
  #pragma unroll
  for (int dt = 0; dt < 8; dt++){
    uint2 val;
    val.x = (unsigned)cvt_pk_bf16(oacc[dt][0]*invl, oacc[dt][1]*invl);
    val.y = (unsigned)cvt_pk_bf16(oacc[dt][2]*invl, oacc[dt][3]*invl);
    *(uint2*)&O2[obase + 16*dt] = val;
  }
}

// ---------------------------------------------------------------------------
// finalmm (reverted to R0-exact): 32-row tiles, dbuf, vmcnt(2).
// ---------------------------------------------------------------------------
__global__ __launch_bounds__(256) void finalmm(
    const ushort_t* __restrict__ O2,    // [8192][1024] bf16
    const ushort_t* __restrict__ Wub,   // [128][1024] bf16
    const float* __restrict__ bu,
    float* __restrict__ out)            // [8192][128]
{
  __shared__ ushort_t As[2][32*32]  __attribute__((aligned(16)));   // 2x2 KB
  __shared__ ushort_t Bs[2][128*32] __attribute__((aligned(16)));   // 2x8 KB
  int bt0 = blockIdx.x * 32;
  int tid = threadIdx.x;
  int w = tid >> 6, ln = tid & 63;
  int lc = ln & 15, lg = ln >> 4;
  int nj = w * 32;
  int srow = ln >> 2;
  int kseg = (ln & 3) * 8;

  f32x4 acc[2][2];
  #pragma unroll
  for (int si = 0; si < 2; si++)
    #pragma unroll
    for (int sj = 0; sj < 2; sj++) acc[si][sj] = (f32x4){0.f,0.f,0.f,0.f};

  const ushort_t* gA = O2  + (size_t)(bt0 + (w & 1)*16 + srow)*1024 + kseg;
  const ushort_t* gB = Wub + (size_t)(w*32 + srow)*1024 + kseg;

  auto stageF = [&](int kk, int bsel){
    int r0 = kk * 32;
    if (w < 2) async_cp16(&As[bsel][w*512], gA + r0);
    async_cp16(&Bs[bsel][w*1024],       gB + r0);
    async_cp16(&Bs[bsel][w*1024 + 512], gB + r0 + 16*1024);
  };

  stageF(0, 0);
  for (int kk = 0; kk < 32; kk++){
    int bsel = kk & 1;
    if (kk + 1 < 32){
      stageF(kk + 1, bsel ^ 1);
      asm volatile("s_waitcnt vmcnt(2)\n\ts_barrier" ::: "memory");
    } else {
      asm volatile("s_waitcnt vmcnt(0)\n\ts_barrier" ::: "memory");
    }
    bf16x8 af[2], bfr[2];
    #pragma unroll
    for (int si = 0; si < 2; si++)
      af[si] = *(const bf16x8*)&As[bsel][(16*si + lc)*32 + 8*lg];
    #pragma unroll
    for (int sj = 0; sj < 2; sj++)
      bfr[sj] = *(const bf16x8*)&Bs[bsel][(nj + 16*sj + lc)*32 + 8*lg];
    #pragma unroll
    for (int si = 0; si < 2; si++)
      #pragma unroll
      for (int sj = 0; sj < 2; sj++)
        acc[si][sj] = __builtin_amdgcn_mfma_f32_16x16x32_bf16(af[si], bfr[sj],
                                                              acc[si][sj], 0,0,0);
    asm volatile("s_barrier" ::: "memory");
  }

  float bv[2];
  #pragma unroll
  for (int sj = 0; sj < 2; sj++) bv[sj] = bu[nj + 16*sj + lc];
  #pragma unroll
  for (int si = 0; si < 2; si++)
    #pragma unroll
    for (int r = 0; r < 4; r++){
      int t = bt0 + 16*si + 4*lg + r;
      #pragma unroll
      for (int sj = 0; sj < 2; sj++)
        out[(size_t)t*128 + nj + 16*sj + lc] = silu_f(acc[si][sj][r] + bv[sj]);
    }
}

// ---------------------------------------------------------------------------
extern "C" void kernel_launch(void* const* d_in, const int* in_sizes, int n_in,
                              void* d_out, int out_size, void* d_ws, size_t ws_size,
                              hipStream_t stream) {
  const float* x  = (const float*)d_in[0];
  const float* Wq = (const float*)d_in[1];
  const float* bq = (const float*)d_in[2];
  const float* Wk = (const float*)d_in[3];
  const float* bk = (const float*)d_in[4];
  const float* Wv = (const float*)d_in[5];
  const float* Wu = (const float*)d_in[6];
  const float* bu = (const float*)d_in[7];
  float* out = (float*)d_out;

  // Workspace layout (generous slack; Xpad is 2,105,344 B)
  char* ws = (char*)d_ws;
  ushort_t* Q2   = (ushort_t*)(ws + 0);            // 16 MB
  ushort_t* K2   = (ushort_t*)(ws + 16777216);     // 16 MB
  ushort_t* V2t  = (ushort_t*)(ws + 33554432);     // 16 MB
  ushort_t* O2   = (ushort_t*)(ws + 50331648);     // 16 MB (bf16 [8192][1024])
  ushort_t* Xpad = (ushort_t*)(ws + 67108864);     // 2.008 MB
  ushort_t* W2p  = (ushort_t*)(ws + 70254592);     // 2.5 MB
  ushort_t* Wvp  = (ushort_t*)(ws + 73400320);     // 0.25 MB
  ushort_t* Wub  = (ushort_t*)(ws + 74448896);     // 0.25 MB

  prep<<<dim3(4228, 1, 1), 256, 0, stream>>>(Wq, Wk, Wv, Wu, x,
                                             W2p, Wvp, Wub, Xpad);

  gemm_qkv<<<dim3(24, 64, 1), 256, 0, stream>>>(Xpad, W2p, Wvp, bq, bk,
                                                Q2, K2, V2t);

  attn<<<dim3(512, 1, 1), 256, 0, stream>>>(Q2, K2, V2t, O2);
  finalmm<<<dim3(256, 1, 1), 256, 0, stream>>>(O2, Wub, bu, out);
}

// Round 7
// 200.673 us; speedup vs baseline: 1.4010x; 1.0060x over previous
//
#include <hip/hip_runtime.h>
#include <hip/hip_bf16.h>
#include <stdint.h>

// B=4, T=2048, K(=D)=128, H=8, KS=5, DIL=2, PAD=8, M=B*H=32
// scale = 128^0.25 ; inv = 0.29730177875068026

typedef __attribute__((ext_vector_type(8))) short bf16x8;
typedef __attribute__((ext_vector_type(4))) float f32x4;
typedef __attribute__((ext_vector_type(4))) int   i32x4;
typedef unsigned short ushort_t;

__device__ __forceinline__ unsigned short f2bf(float x){
  union{float f; unsigned u;} v; v.f = x;
  unsigned r = v.u + 0x7FFFu + ((v.u >> 16) & 1u);   // RNE
  return (unsigned short)(r >> 16);
}
__device__ __forceinline__ float silu_f(float x){ return x / (1.f + __expf(-x)); }

__device__ __forceinline__ int cvt_pk_bf16(float lo, float hi){
  int r;
  asm("v_cvt_pk_bf16_f32 %0, %1, %2" : "=v"(r) : "v"(lo), "v"(hi));
  return r;
}

// VALU cross-lane swaps (gfx950). After p32: a=[a.l0-31|b.l0-31], b=[a.l32-63|b.l32-63].
// After p16: a=[a.r0|b.r0|a.r2|b.r2], b=[a.r1|b.r1|a.r3|b.r3]  (rows of 16 lanes).
__device__ __forceinline__ void permlane32_swap(int &a, int &b){
  asm volatile("v_permlane32_swap_b32 %0, %1" : "+v"(a), "+v"(b));
}
__device__ __forceinline__ void permlane16_swap(int &a, int &b){
  asm volatile("v_permlane16_swap_b32 %0, %1" : "+v"(a), "+v"(b));
}

__device__ __forceinline__ void async_cp16(void* lds, const void* g){
  __builtin_amdgcn_global_load_lds(
      (const __attribute__((address_space(1))) unsigned int*)g,
      (__attribute__((address_space(3))) unsigned int*)lds, 16, 0, 0);
}

// ---------------------------------------------------------------------------
// prep v2: coalesced + vectorized.  (unchanged, R0 baseline)
// ---------------------------------------------------------------------------
__global__ __launch_bounds__(256) void prep(const float* __restrict__ Wq,
                                            const float* __restrict__ Wk,
                                            const float* __restrict__ Wv,
                                            const float* __restrict__ Wu,
                                            const float* __restrict__ x,
                                            ushort_t* __restrict__ W2p,
                                            ushort_t* __restrict__ Wvp,
                                            ushort_t* __restrict__ Wub,
                                            ushort_t* __restrict__ Xpad){
  __shared__ float row[640];
  int n = blockIdx.x;
  int tid = threadIdx.x;
  if (n < 2048){
    int qk = n >> 10, h = (n >> 7) & 7, d = n & 127;
    const float* src = (qk ? Wk : Wq) + (size_t)(d*8 + h)*640;
    if (tid < 160) *(float4*)&row[tid*4] = *(const float4*)&src[tid*4];
    __syncthreads();
    for (int rp = tid; rp < 640; rp += 256){
      int j = rp >> 7, ci = rp & 127;
      W2p[(size_t)n*640 + rp] = f2bf(row[ci*5 + j]);
    }
  } else if (n < 3072){
    int co = n - 2048;
    if (tid < 32){
      float4 v = *(const float4*)&Wv[(size_t)co*128 + tid*4];
      uint2 pv;
      pv.x = (unsigned)cvt_pk_bf16(v.x, v.y);
      pv.y = (unsigned)cvt_pk_bf16(v.z, v.w);
      *(uint2*)&Wvp[(size_t)co*128 + tid*4] = pv;
    }
  } else if (n < 3200){
    int j = n - 3072;
    float4 v = *(const float4*)&Wu[(size_t)j*1024 + tid*4];
    uint2 pv;
    pv.x = (unsigned)cvt_pk_bf16(v.x, v.y);
    pv.y = (unsigned)cvt_pk_bf16(v.z, v.w);
    *(uint2*)&Wub[(size_t)j*1024 + tid*4] = pv;
  } else {
    int idx = n - 3200;              // 0..1027 ; 257 blocks per batch (2056=8*257)
    int b = idx / 257, rblk = idx - b*257;
    int rt = rblk*8 + (tid >> 5);
    int ci4 = (tid & 31) * 4;
    int t = rt - 8;
    uint2 val; val.x = 0u; val.y = 0u;
    if (t >= 0){
      float4 v = *(const float4*)&x[((size_t)(b*2048 + t))*128 + ci4];
      val.x = (unsigned)cvt_pk_bf16(v.x, v.y);
      val.y = (unsigned)cvt_pk_bf16(v.z, v.w);
    }
    *(uint2*)&Xpad[((size_t)(b*2056 + rt))*128 + ci4] = val;
  }
}

// ---------------------------------------------------------------------------
// gemm_qkv: R0 structure, + __launch_bounds__(256, 4).
// Theory: acc[4][4] (64 f32) + staging state plausibly lands at 129-140 VGPR;
// crossing 128 halves waves/SIMD (m69) -> 2 blocks/CU instead of 4 and the
// 2-phase loop runs latency-naked. Forcing min 4 waves/EU caps VGPR at 128
// (needed live state ~110 -> no spill expected). If VGPR was already <=128
// this is a no-op.
// ---------------------------------------------------------------------------
__global__ __launch_bounds__(256, 4) void gemm_qkv(
    const ushort_t* __restrict__ Xpad,  // [4][2056][128]
    const ushort_t* __restrict__ W2p,   // [2048][640]
    const ushort_t* __restrict__ Wvp,   // [1024][128]
    const float* __restrict__ bq, const float* __restrict__ bk,
    ushort_t* __restrict__ Q2, ushort_t* __restrict__ K2,
    ushort_t* __restrict__ V2t)
{
  __shared__ ushort_t As[2][128*32] __attribute__((aligned(16)));
  __shared__ ushort_t Bs[2][128*32] __attribute__((aligned(16)));
  int bt0 = blockIdx.y * 128;
  int tid = threadIdx.x;
  int w = tid >> 6, ln = tid & 63;
  int lc = ln & 15, lg = ln >> 4;
  int mi = (w & 1) * 64, nj = (w >> 1) * 64;
  int srow = ln >> 2;
  int kseg = (ln & 3) * 8;
  int b = bt0 >> 11, tl0 = bt0 & 2047;

  f32x4 acc[4][4];
  #pragma unroll
  for (int si = 0; si < 4; si++)
    #pragma unroll
    for (int sj = 0; sj < 4; sj++) acc[si][sj] = (f32x4){0.f,0.f,0.f,0.f};

  if (blockIdx.x < 16){
    int n0 = blockIdx.x * 128;
    const ushort_t* gA = Xpad + (size_t)(b*2056 + tl0 + w*32 + srow)*128 + kseg;
    const ushort_t* gB = W2p + (size_t)(n0  + w*32 + srow)*640 + kseg;

    auto stageAB = [&](int kk, int bsel){
      int j = kk >> 2, ci0 = (kk & 3) * 32;
      int r0 = kk * 32;
      const ushort_t* a0 = gA + (size_t)(2*j)*128 + ci0;
      async_cp16(&As[bsel][w*1024],       a0);
      async_cp16(&As[bsel][w*1024 + 512], a0 + 16*128);
      async_cp16(&Bs[bsel][w*1024],       gB + r0);
      async_cp16(&Bs[bsel][w*1024 + 512], gB + r0 + 16*640);
    };

    stageAB(0, 0);
    for (int kk = 0; kk < 20; kk++){
      int bsel = kk & 1;
      if (kk + 1 < 20){
        stageAB(kk + 1, bsel ^ 1);
        asm volatile("s_waitcnt vmcnt(4)\n\ts_barrier" ::: "memory");
      } else {
        asm volatile("s_waitcnt vmcnt(0)\n\ts_barrier" ::: "memory");
      }
      bf16x8 af[4], bfr[4];
      #pragma unroll
      for (int si = 0; si < 4; si++)
        af[si] = *(const bf16x8*)&As[bsel][(mi + 16*si + lc)*32 + 8*lg];
      #pragma unroll
      for (int sj = 0; sj < 4; sj++)
        bfr[sj] = *(const bf16x8*)&Bs[bsel][(nj + 16*sj + lc)*32 + 8*lg];
      #pragma unroll
      for (int si = 0; si < 4; si++)
        #pragma unroll
        for (int sj = 0; sj < 4; sj++)
          acc[si][sj] = __builtin_amdgcn_mfma_f32_16x16x32_bf16(af[si], bfr[sj],
                                                                acc[si][sj], 0,0,0);
      asm volatile("s_barrier" ::: "memory");
    }

    const float inv_scale = 0.29730177875068026f;
    int qk = n0 >> 10, h = (n0 >> 7) & 7;
    const float* bias = qk ? bk : bq;
    ushort_t* dst = qk ? K2 : Q2;
    float bv[4];
    #pragma unroll
    for (int sj = 0; sj < 4; sj++) bv[sj] = bias[(nj + 16*sj + lc)*8 + h];

    #pragma unroll
    for (int si = 0; si < 4; si++){
      int btb = bt0 + mi + 16*si + 4*lg;
      #pragma unroll
      for (int r = 0; r < 4; r++){
        int t = btb + r;
        int bb = t >> 11, tl = t & 2047;
        size_t rowoff = ((size_t)(bb*8 + (tl >> 8))*2048 + (tl & 255)*8 + h)*128;
        #pragma unroll
        for (int sj = 0; sj < 4; sj++){
          int d = nj + 16*sj + lc;
          dst[rowoff + d] = f2bf(silu_f(acc[si][sj][r] + bv[sj]) * inv_scale);
        }
      }
    }
  } else {
    int n0 = (blockIdx.x - 16) * 128;
    const ushort_t* gA = Xpad + (size_t)(b*2056 + 8 + tl0 + w*32 + srow)*128 + kseg;
    const ushort_t* gB = Wvp  + (size_t)(n0 + w*32 + srow)*128 + kseg;

    auto stageV = [&](int kk, int bsel){
      int r0 = kk * 32;
      async_cp16(&As[bsel][w*1024],       gA + r0);
      async_cp16(&As[bsel][w*1024 + 512], gA + r0 + 16*128);
      async_cp16(&Bs[bsel][w*1024],       gB + r0);
      async_cp16(&Bs[bsel][w*1024 + 512], gB + r0 + 16*128);
    };

    stageV(0, 0);
    for (int kk = 0; kk < 4; kk++){
      int bsel = kk & 1;
      if (kk + 1 < 4){
        stageV(kk + 1, bsel ^ 1);
        asm volatile("s_waitcnt vmcnt(4)\n\ts_barrier" ::: "memory");
      } else {
        asm volatile("s_waitcnt vmcnt(0)\n\ts_barrier" ::: "memory");
      }
      bf16x8 af[4], bfr[4];
      #pragma unroll
      for (int si = 0; si < 4; si++)
        af[si] = *(const bf16x8*)&As[bsel][(mi + 16*si + lc)*32 + 8*lg];
      #pragma unroll
      for (int sj = 0; sj < 4; sj++)
        bfr[sj] = *(const bf16x8*)&Bs[bsel][(nj + 16*sj + lc)*32 + 8*lg];
      #pragma unroll
      for (int si = 0; si < 4; si++)
        #pragma unroll
        for (int sj = 0; sj < 4; sj++)
          acc[si][sj] = __builtin_amdgcn_mfma_f32_16x16x32_bf16(af[si], bfr[sj],
                                                                acc[si][sj], 0,0,0);
      asm volatile("s_barrier" ::: "memory");
    }

    #pragma unroll
    for (int si = 0; si < 4; si++){
      int btb = bt0 + mi + 16*si + 4*lg;
      #pragma unroll
      for (int r = 0; r < 4; r++){
        int t = btb + r;
        int bb = t >> 11, tl = t & 2047;
        int mm = bb*8 + (tl >> 8);
        int tpb = (tl & 255)*8;
        #pragma unroll
        for (int sj = 0; sj < 4; sj++){
          int co = n0 + nj + 16*sj + lc;
          int d = co >> 3, hh = co & 7;
          V2t[((size_t)mm*128 + d)*2048 + tpb + hh] = f2bf(silu_f(acc[si][sj][r]));
        }
      }
    }
  }
}

// ---------------------------------------------------------------------------
// Flash attention — R6 exact (best known: ~80us, VGPR 88, conflicts 0).
// Frozen R0 structure + permlane P-transpose (no LDS bpermute).
// ---------------------------------------------------------------------------
__global__ __launch_bounds__(256) void attn(
    const ushort_t* __restrict__ Q2,   // [32][2048][128]
    const ushort_t* __restrict__ K2,   // [32][2048][128]
    const ushort_t* __restrict__ V2t,  // [32][128][2048]
    ushort_t* __restrict__ O2)         // [8192][1024] bf16
{
  __shared__ i32x4 kbuf[2][1024];      // [buf][(st*4+c)*64 + lane]  16KB each
  __shared__ i32x4 vbuf[2][1024];      // [buf][(dt*2+ks)*64 + lane] 16KB each

  int bid = blockIdx.x;                      // 512 blocks
  int m   = ((bid & 7) << 2) | ((bid >> 3) & 3);  // XCD-L2 locality swizzle
  int ip  = bid >> 5;                        // pair index 0..15
  int tid = threadIdx.x;
  int w = tid >> 6, l = tid & 63;
  int lc = l & 15, lg = l >> 4;

  int iA = 31 - ip, iB = ip;
  int ntA = iA + 1;
  const int nt = 33;

  const size_t mQ = (size_t)m * 2048;
  const ushort_t* Kbase = K2  + mQ * 128;
  const ushort_t* Vbase = V2t + (size_t)m * 128 * 2048;
  int hb = m & 7, bI = m >> 3;

  auto stage = [&](int s0, int bsel){
    const ushort_t* krow = Kbase + (size_t)(s0 + w*16 + lc)*128 + 8*lg;
    #pragma unroll
    for (int c = 0; c < 4; c++)
      async_cp16(&kbuf[bsel][(w*4 + c)*64], krow + 32*c);
    #pragma unroll
    for (int j = 0; j < 4; j++){
      int dt = w*2 + (j >> 1);
      const ushort_t* vrow = Vbase + (size_t)(dt*16 + lc)*2048
                             + s0 + (j & 1)*32 + 8*lg;
      async_cp16(&vbuf[bsel][(w*4 + j)*64], vrow);
    }
  };

  int qb = iA*64 + w*16;
  bf16x8 qfrag[4];
  {
    const ushort_t* qp = Q2 + (mQ + qb + lc)*128 + 8*lg;
    #pragma unroll
    for (int c = 0; c < 4; c++) qfrag[c] = *(const bf16x8*)(qp + 32*c);
  }
  f32x4 oacc[8];
  #pragma unroll
  for (int dt = 0; dt < 8; dt++) oacc[dt] = (f32x4){0.f,0.f,0.f,0.f};
  float lrow = 0.f;

  const float LOG2E = 1.4426950408889634f;
  const float EOFF  = -11.541560327111707f;   // -8 * log2(e)

  stage(0, 0);

  for (int step = 0; step < nt; step++){
    if (step == ntA){
      float lt = lrow;
      lt += __shfl_xor(lt, 16);
      lt += __shfl_xor(lt, 32);
      float invl = 1.f / lt;
      size_t obase = ((size_t)(bI*2048 + qb + lc))*1024 + hb*128 + 4*lg;
      #pragma unroll
      for (int dt = 0; dt < 8; dt++){
        uint2 val;
        val.x = (unsigned)cvt_pk_bf16(oacc[dt][0]*invl, oacc[dt][1]*invl);
        val.y = (unsigned)cvt_pk_bf16(oacc[dt][2]*invl, oacc[dt][3]*invl);
        *(uint2*)&O2[obase + 16*dt] = val;
      }
      qb = iB*64 + w*16;
      const ushort_t* qp = Q2 + (mQ + qb + lc)*128 + 8*lg;
      #pragma unroll
      for (int c = 0; c < 4; c++) qfrag[c] = *(const bf16x8*)(qp + 32*c);
      #pragma unroll
      for (int dt = 0; dt < 8; dt++) oacc[dt] = (f32x4){0.f,0.f,0.f,0.f};
      lrow = 0.f;
    }
    int local = (step < ntA) ? step : step - ntA;
    bool isLast = (step == ntA - 1) || (step == nt - 1);
    int s0 = local * 64;
    int bsel = step & 1;

    if (step + 1 < nt){
      int nl = (step + 1 < ntA) ? step + 1 : step + 1 - ntA;
      stage(nl*64, bsel ^ 1);
      asm volatile("s_waitcnt vmcnt(8)\n\ts_barrier" ::: "memory");
    } else {
      asm volatile("s_waitcnt vmcnt(0)\n\ts_barrier" ::: "memory");
    }

    f32x4 sacc[4];
    #pragma unroll
    for (int st = 0; st < 4; st++){
      f32x4 a2 = (f32x4){0.f,0.f,0.f,0.f};
      #pragma unroll
      for (int c = 0; c < 4; c++){
        bf16x8 kf = *(bf16x8*)&kbuf[bsel][(st*4 + c)*64 + l];
        a2 = __builtin_amdgcn_mfma_f32_16x16x32_bf16(kf, qfrag[c], a2, 0, 0, 0);
      }
      sacc[st] = a2;
    }
    if (isLast){
      int qg = qb + lc;
      #pragma unroll
      for (int st = 0; st < 4; st++)
        #pragma unroll
        for (int r = 0; r < 4; r++){
          int sg = s0 + st*16 + 4*lg + r;
          if (sg > qg) sacc[st][r] = -1e30f;
        }
    }

    float p_[4][4];
    #pragma unroll
    for (int st = 0; st < 4; st++)
      #pragma unroll
      for (int r = 0; r < 4; r++){
        float sv = fminf(fmaf(sacc[st][r], LOG2E, EOFF), 108.f);
        float pv = __builtin_amdgcn_exp2f(sv);
        p_[st][r] = pv;
        lrow += pv;
      }

    #pragma unroll
    for (int ks = 0; ks < 2; ks++){
      union { int i[4]; bf16x8 v; } bfr;
      #pragma unroll
      for (int pa = 0; pa < 2; pa++){
        int x = cvt_pk_bf16(p_[2*ks][2*pa],   p_[2*ks][2*pa+1]);   // pk0[pa]
        int y = cvt_pk_bf16(p_[2*ks+1][2*pa], p_[2*ks+1][2*pa+1]); // pk1[pa]
        permlane32_swap(x, y);   // x=[pk0.lo|pk1.lo]  y=[pk0.hi|pk1.hi]
        permlane16_swap(x, y);   // x -> words t=0, y -> words t=1
        bfr.i[pa]     = x;       // w2 = pa      (t=0)
        bfr.i[pa + 2] = y;       // w2 = pa + 2  (t=1)
      }
      #pragma unroll
      for (int dt = 0; dt < 8; dt++){
        bf16x8 vf = *(bf16x8*)&vbuf[bsel][(dt*2 + ks)*64 + l];
        oacc[dt] = __builtin_amdgcn_mfma_f32_16x16x32_bf16(vf, bfr.v, oacc[dt], 0, 0, 0);
      }
    }
    asm volatile("s_barrier" ::: "memory");
  }

  float lt = lrow;
  lt += __shfl_xor(lt, 16);
  lt += __shfl_xor(lt, 32);
  float invl = 1.f / lt;
  size_t obase = ((size_t)(bI*2048 + qb + lc))*1024 + hb*128 + 4*lg;
  #pragma unroll
  for (int dt = 0; dt < 8; dt++){
    uint2 val;
    val.x = (unsigned)cvt_pk_bf16(oacc[dt][0]*invl, oacc[dt][1]*invl);
    val.y = (unsigned)cvt_pk_bf16(oacc[dt][2]*invl, oacc[dt][3]*invl);
    *(uint2*)&O2[obase + 16*dt] = val;
  }
}

// ---------------------------------------------------------------------------
// finalmm: R0-exact structure + __launch_bounds__(256, 4) (trivially met).
// ---------------------------------------------------------------------------
__global__ __launch_bounds__(256, 4) void finalmm(
    const ushort_t* __restrict__ O2,    // [8192][1024] bf16
    const ushort_t* __restrict__ Wub,   // [128][1024] bf16
    const float* __restrict__ bu,
    float* __restrict__ out)            // [8192][128]
{
  __shared__ ushort_t As[2][32*32]  __attribute__((aligned(16)));   // 2x2 KB
  __shared__ ushort_t Bs[2][128*32] __attribute__((aligned(16)));   // 2x8 KB
  int bt0 = blockIdx.x * 32;
  int tid = threadIdx.x;
  int w = tid >> 6, ln = tid & 63;
  int lc = ln & 15, lg = ln >> 4;
  int nj = w * 32;
  int srow = ln >> 2;
  int kseg = (ln & 3) * 8;

  f32x4 acc[2][2];
  #pragma unroll
  for (int si = 0; si < 2; si++)
    #pragma unroll
    for (int sj = 0; sj < 2; sj++) acc[si][sj] = (f32x4){0.f,0.f,0.f,0.f};

  const ushort_t* gA = O2  + (size_t)(bt0 + (w & 1)*16 + srow)*1024 + kseg;
  const ushort_t* gB = Wub + (size_t)(w*32 + srow)*1024 + kseg;

  auto stageF = [&](int kk, int bsel){
    int r0 = kk * 32;
    if (w < 2) async_cp16(&As[bsel][w*512], gA + r0);
    async_cp16(&Bs[bsel][w*1024],       gB + r0);
    async_cp16(&Bs[bsel][w*1024 + 512], gB + r0 + 16*1024);
  };

  stageF(0, 0);
  for (int kk = 0; kk < 32; kk++){
    int bsel = kk & 1;
    if (kk + 1 < 32){
      stageF(kk + 1, bsel ^ 1);
      asm volatile("s_waitcnt vmcnt(2)\n\ts_barrier" ::: "memory");
    } else {
      asm volatile("s_waitcnt vmcnt(0)\n\ts_barrier" ::: "memory");
    }
    bf16x8 af[2], bfr[2];
    #pragma unroll
    for (int si = 0; si < 2; si++)
      af[si] = *(const bf16x8*)&As[bsel][(16*si + lc)*32 + 8*lg];
    #pragma unroll
    for (int sj = 0; sj < 2; sj++)
      bfr[sj] = *(const bf16x8*)&Bs[bsel][(nj + 16*sj + lc)*32 + 8*lg];
    #pragma unroll
    for (int si = 0; si < 2; si++)
      #pragma unroll
      for (int sj = 0; sj < 2; sj++)
        acc[si][sj] = __builtin_amdgcn_mfma_f32_16x16x32_bf16(af[si], bfr[sj],
                                                              acc[si][sj], 0,0,0);
    asm volatile("s_barrier" ::: "memory");
  }

  float bv[2];
  #pragma unroll
  for (int sj = 0; sj < 2; sj++) bv[sj] = bu[nj + 16*sj + lc];
  #pragma unroll
  for (int si = 0; si < 2; si++)
    #pragma unroll
    for (int r = 0; r < 4; r++){
      int t = bt0 + 16*si + 4*lg + r;
      #pragma unroll
      for (int sj = 0; sj < 2; sj++)
        out[(size_t)t*128 + nj + 16*sj + lc] = silu_f(acc[si][sj][r] + bv[sj]);
    }
}

// ---------------------------------------------------------------------------
extern "C" void kernel_launch(void* const* d_in, const int* in_sizes, int n_in,
                              void* d_out, int out_size, void* d_ws, size_t ws_size,
                              hipStream_t stream) {
  const float* x  = (const float*)d_in[0];
  const float* Wq = (const float*)d_in[1];
  const float* bq = (const float*)d_in[2];
  const float* Wk = (const float*)d_in[3];
  const float* bk = (const float*)d_in[4];
  const float* Wv = (const float*)d_in[5];
  const float* Wu = (const float*)d_in[6];
  const float* bu = (const float*)d_in[7];
  float* out = (float*)d_out;

  // Workspace layout (generous slack; Xpad is 2,105,344 B)
  char* ws = (char*)d_ws;
  ushort_t* Q2   = (ushort_t*)(ws + 0);            // 16 MB
  ushort_t* K2   = (ushort_t*)(ws + 16777216);     // 16 MB
  ushort_t* V2t  = (ushort_t*)(ws + 33554432);     // 16 MB
  ushort_t* O2   = (ushort_t*)(ws + 50331648);     // 16 MB (bf16 [8192][1024])
  ushort_t* Xpad = (ushort_t*)(ws + 67108864);     // 2.008 MB
  ushort_t* W2p  = (ushort_t*)(ws + 70254592);     // 2.5 MB
  ushort_t* Wvp  = (ushort_t*)(ws + 73400320);     // 0.25 MB
  ushort_t* Wub  = (ushort_t*)(ws + 74448896);     // 0.25 MB

  prep<<<dim3(4228, 1, 1), 256, 0, stream>>>(Wq, Wk, Wv, Wu, x,
                                             W2p, Wvp, Wub, Xpad);

  gemm_qkv<<<dim3(24, 64, 1), 256, 0, stream>>>(Xpad, W2p, Wvp, bq, bk,
                                                Q2, K2, V2t);

  attn<<<dim3(512, 1, 1), 256, 0, stream>>>(Q2, K2, V2t, O2);
  finalmm<<<dim3(256, 1, 1), 256, 0, stream>>>(O2, Wub, bu, out);
}